// Round 1
// baseline (320.254 us; speedup 1.0000x reference)
//
#include <hip/hip_runtime.h>
#include <cmath>

// Decoder block: LN1 -> QKV -> (swapped) causal attention -> residual -> LN2 -> MLP(GELU) -> residual
// B=2, T=2048, C=768, H=12, dh=64. All GEMMs bf16 MFMA 16x16x32, fp32 accumulate.

#define BB 2
#define TT 2048
#define CC 768
#define HH 12
#define DH 64
#define NROWS (BB*TT)   // 4096

typedef __attribute__((ext_vector_type(8))) short bf16x8;
typedef __attribute__((ext_vector_type(4))) float f32x4;

__device__ __forceinline__ float bf2f(unsigned short u){
  union { unsigned int i; float f; } x; x.i = ((unsigned int)u) << 16; return x.f;
}
__device__ __forceinline__ unsigned short f2bf(float f){
  union { float f; unsigned int i; } x; x.f = f;
  unsigned int u = x.i;
  return (unsigned short)((u + 0x7FFFu + ((u >> 16) & 1u)) >> 16);
}
// XOR-swizzle for [rows][64] bf16 LDS tiles (128B rows): kills the 16-way
// bank conflict on ds_read_b128 column-slices. Returns ELEMENT index.
__device__ __forceinline__ int swz(int r, int c){
  int b = (r << 7) + (c << 1);
  b ^= (r & 7) << 4;
  return b >> 1;
}
__device__ __forceinline__ float wred_sum(float v){
  #pragma unroll
  for(int m = 1; m < 64; m <<= 1) v += __shfl_xor(v, m, 64);
  return v;
}
__device__ __forceinline__ float gelu_exact(float x){
  return 0.5f * x * (1.0f + erff(x * 0.70710678118654752f));
}

// ---------------- weight transpose+convert: in (K,N) f32 -> out (N,K) bf16 ----------------
__global__ __launch_bounds__(256) void transpose_convert(const float* __restrict__ in,
                                                         unsigned short* __restrict__ out,
                                                         int K, int N){
  __shared__ float tile[32][33];
  int n0 = blockIdx.x * 32, k0 = blockIdx.y * 32;
  int t = threadIdx.x; int c = t & 31; int r0 = t >> 5; // 8 rows per pass
  #pragma unroll
  for(int p = 0; p < 4; p++){
    int r = r0 + p * 8;
    tile[r][c] = in[(size_t)(k0 + r) * N + n0 + c];
  }
  __syncthreads();
  #pragma unroll
  for(int p = 0; p < 4; p++){
    int r = r0 + p * 8;
    out[(size_t)(n0 + r) * K + k0 + c] = f2bf(tile[c][r]);
  }
}

__global__ __launch_bounds__(256) void concat_bias(const float* __restrict__ bq,
                                                   const float* __restrict__ bk,
                                                   const float* __restrict__ bv,
                                                   float* __restrict__ bqkv){
  int i = blockIdx.x * 256 + threadIdx.x;
  if(i < 3 * CC) bqkv[i] = (i < CC) ? bq[i] : (i < 2 * CC) ? bk[i - CC] : bv[i - 2 * CC];
}

// ---------------- LayerNorm (fp32 in, fp32+bf16 out), one block per row, C=768 ----------------
__global__ __launch_bounds__(256) void ln_kernel(const float* __restrict__ in,
                                                 const float* __restrict__ gm,
                                                 const float* __restrict__ bt,
                                                 float* __restrict__ out_f,
                                                 unsigned short* __restrict__ out_b){
  int r = blockIdx.x; int t = threadIdx.x;
  const float* row = in + (size_t)r * CC;
  float v0 = row[t], v1 = row[t + 256], v2 = row[t + 512];
  float s = wred_sum(v0 + v1 + v2);
  __shared__ float red[4];
  if((t & 63) == 0) red[t >> 6] = s;
  __syncthreads();
  float mu = (red[0] + red[1] + red[2] + red[3]) * (1.0f / CC);
  float d0 = v0 - mu, d1 = v1 - mu, d2 = v2 - mu;
  float q = wred_sum(d0 * d0 + d1 * d1 + d2 * d2);
  __shared__ float red2[4];
  if((t & 63) == 0) red2[t >> 6] = q;
  __syncthreads();
  float var = (red2[0] + red2[1] + red2[2] + red2[3]) * (1.0f / CC);
  float rinv = rsqrtf(var + 1e-3f);
  float o0 = d0 * rinv * gm[t]       + bt[t];
  float o1 = d1 * rinv * gm[t + 256] + bt[t + 256];
  float o2 = d2 * rinv * gm[t + 512] + bt[t + 512];
  size_t base = (size_t)r * CC;
  if(out_f){ out_f[base + t] = o0; out_f[base + t + 256] = o1; out_f[base + t + 512] = o2; }
  out_b[base + t] = f2bf(o0); out_b[base + t + 256] = f2bf(o1); out_b[base + t + 512] = f2bf(o2);
}

// ---------------- GEMM: C[M,N] = A[M,K](bf16) x Bt[N,K](bf16) + bias, 128x128 tile, BK=64 ----
// MODE 0: +bias, store bf16    (QKV)
// MODE 1: +bias, GELU, bf16    (MLP1)
// MODE 2: +bias, +resid, f32   (MLP2 -> d_out)
template<int MODE>
__global__ __launch_bounds__(256) void gemm_bt(const unsigned short* __restrict__ A,
                                               const unsigned short* __restrict__ Bt,
                                               const float* __restrict__ bias,
                                               const float* __restrict__ resid,
                                               void* __restrict__ outp,
                                               int M, int N, int K){
  __shared__ unsigned short As[128 * 64];
  __shared__ unsigned short Bs[128 * 64];
  int m0 = blockIdx.y * 128, n0 = blockIdx.x * 128;
  int t = threadIdx.x; int w = t >> 6; int l = t & 63;
  int g = l >> 4; int lc = l & 15;
  int wm = w >> 1, wn = w & 1;
  f32x4 zero4 = {0.f, 0.f, 0.f, 0.f};
  f32x4 acc[4][4];
  #pragma unroll
  for(int mi = 0; mi < 4; mi++)
    #pragma unroll
    for(int ni = 0; ni < 4; ni++) acc[mi][ni] = zero4;

  for(int ks = 0; ks < K; ks += 64){
    #pragma unroll
    for(int p = 0; p < 4; p++){
      int idx = p * 256 + t; int r = idx >> 3; int c = (idx & 7) * 8;
      *(bf16x8*)&As[swz(r, c)] = *(const bf16x8*)(A  + (size_t)(m0 + r) * K + ks + c);
      *(bf16x8*)&Bs[swz(r, c)] = *(const bf16x8*)(Bt + (size_t)(n0 + r) * K + ks + c);
    }
    __syncthreads();
    #pragma unroll
    for(int kk = 0; kk < 2; kk++){
      bf16x8 af[4], bfv[4];
      #pragma unroll
      for(int mi = 0; mi < 4; mi++) af[mi]  = *(const bf16x8*)&As[swz(wm * 64 + mi * 16 + lc, kk * 32 + g * 8)];
      #pragma unroll
      for(int ni = 0; ni < 4; ni++) bfv[ni] = *(const bf16x8*)&Bs[swz(wn * 64 + ni * 16 + lc, kk * 32 + g * 8)];
      #pragma unroll
      for(int mi = 0; mi < 4; mi++)
        #pragma unroll
        for(int ni = 0; ni < 4; ni++)
          acc[mi][ni] = __builtin_amdgcn_mfma_f32_16x16x32_bf16(af[mi], bfv[ni], acc[mi][ni], 0, 0, 0);
    }
    __syncthreads();
  }
  // epilogue: C/D layout col=lane&15, row=(lane>>4)*4+reg  [m89-verified]
  #pragma unroll
  for(int mi = 0; mi < 4; mi++)
    #pragma unroll
    for(int ni = 0; ni < 4; ni++){
      int col = n0 + wn * 64 + ni * 16 + lc;
      float bvv = bias[col];
      #pragma unroll
      for(int rr = 0; rr < 4; rr++){
        int row = m0 + wm * 64 + mi * 16 + g * 4 + rr;
        float v = acc[mi][ni][rr] + bvv;
        size_t idx = (size_t)row * N + col;
        if(MODE == 1) v = gelu_exact(v);
        if(MODE == 2) ((float*)outp)[idx] = v + resid[idx];
        else          ((unsigned short*)outp)[idx] = f2bf(v);
      }
    }
}

// ---------------- V transpose: qkv v-part (B,T,H,dh) -> vt (B,H,dh,T) ----------------
__global__ __launch_bounds__(256) void transpose_v(const unsigned short* __restrict__ qkv,
                                                   unsigned short* __restrict__ vt){
  __shared__ unsigned short tile[64][65];
  int t0 = blockIdx.x * 64; int bh = blockIdx.y;
  int b = bh / HH, h = bh % HH;
  int t = threadIdx.x;
  #pragma unroll
  for(int p = 0; p < 2; p++){
    int idx = p * 256 + t; int r = idx >> 3; int c = (idx & 7) * 8;
    bf16x8 v = *(const bf16x8*)(qkv + (size_t)(b * TT + t0 + r) * (3 * CC) + 2 * CC + h * DH + c);
    #pragma unroll
    for(int e = 0; e < 8; e++) tile[r][c + e] = (unsigned short)v[e];
  }
  __syncthreads();
  #pragma unroll
  for(int p = 0; p < 2; p++){
    int idx = p * 256 + t; int d = idx >> 3; int c = (idx & 7) * 8;
    bf16x8 v;
    #pragma unroll
    for(int e = 0; e < 8; e++) v[e] = (short)tile[c + e][d];
    *(bf16x8*)(vt + (size_t)(bh * DH + d) * TT + t0 + c) = v;
  }
}

// ---------------- Flash attention (reference semantics: score[i,j] = k_i . q_j, mask j<=i) ----
// grid (T/64, B*H); block 256 = 4 waves; wave w owns rows i0+w*16..+15.
// Writes x1 = xln + attn_out (fused residual).
__global__ __launch_bounds__(256) void attn_kernel(const unsigned short* __restrict__ qkv,
                                                   const unsigned short* __restrict__ vt,
                                                   const float* __restrict__ xln,
                                                   float* __restrict__ x1){
  __shared__ unsigned short lds_q[64 * 64];
  __shared__ unsigned short lds_v[64 * 64];
  __shared__ unsigned short lds_p[4 * 16 * 64];
  int bx = blockIdx.x; int bh = blockIdx.y;
  int b = bh / HH, h = bh % HH;
  int i0 = bx * 64;
  int t = threadIdx.x; int w = t >> 6; int l = t & 63;
  int g = l >> 4; int lc = l & 15;

  // A-fragments: rows of k (the "query" of the swapped attention), d contiguous
  bf16x8 afr[2];
  int irow = i0 + w * 16 + lc;
  #pragma unroll
  for(int kk = 0; kk < 2; kk++)
    afr[kk] = *(const bf16x8*)(qkv + (size_t)(b * TT + irow) * (3 * CC) + CC + h * DH + kk * 32 + g * 8);

  f32x4 zero4 = {0.f, 0.f, 0.f, 0.f};
  float m[4], lsum[4]; f32x4 o[4];
  #pragma unroll
  for(int rr = 0; rr < 4; rr++){ m[rr] = -INFINITY; lsum[rr] = 0.f; }
  #pragma unroll
  for(int ds = 0; ds < 4; ds++) o[ds] = zero4;

  unsigned short* pw = lds_p + w * (16 * 64);

  for(int jt = 0; jt <= bx; jt++){
    int j0 = jt * 64;
    // stage q rows (j) and v^T rows (d) for this j-tile
    #pragma unroll
    for(int p = 0; p < 2; p++){
      int idx = p * 256 + t; int r = idx >> 3; int c = (idx & 7) * 8;
      bf16x8 vq = *(const bf16x8*)(qkv + (size_t)(b * TT + j0 + r) * (3 * CC) + h * DH + c);
      *(bf16x8*)&lds_q[swz(r, c)] = vq;
      bf16x8 vv = *(const bf16x8*)(vt + (size_t)(bh * DH + r) * TT + j0 + c);
      *(bf16x8*)&lds_v[swz(r, c)] = vv;
    }
    __syncthreads();

    // scores: D[i(16) x j(64)] per wave
    f32x4 sf[4];
    #pragma unroll
    for(int js = 0; js < 4; js++){
      sf[js] = zero4;
      #pragma unroll
      for(int kk = 0; kk < 2; kk++){
        bf16x8 bq = *(const bf16x8*)&lds_q[swz(js * 16 + lc, kk * 32 + g * 8)];
        sf[js] = __builtin_amdgcn_mfma_f32_16x16x32_bf16(afr[kk], bq, sf[js], 0, 0, 0);
      }
    }
    // scale, causal mask, online softmax
    int ig_base = i0 + w * 16 + g * 4;
    #pragma unroll
    for(int rr = 0; rr < 4; rr++){
      float mx = -INFINITY;
      #pragma unroll
      for(int js = 0; js < 4; js++){
        float sv = sf[js][rr] * 0.125f;
        int jg = j0 + js * 16 + lc;
        if(jg > ig_base + rr) sv = -INFINITY;
        sf[js][rr] = sv;
        mx = fmaxf(mx, sv);
      }
      #pragma unroll
      for(int d = 1; d < 16; d <<= 1) mx = fmaxf(mx, __shfl_xor(mx, d, 64));
      float mn = fmaxf(m[rr], mx);
      float al = expf(m[rr] - mn);
      m[rr] = mn;
      lsum[rr] *= al;
      #pragma unroll
      for(int ds = 0; ds < 4; ds++) o[ds][rr] *= al;
      float rsum = 0.f;
      #pragma unroll
      for(int js = 0; js < 4; js++){
        float p = expf(sf[js][rr] - mn);
        sf[js][rr] = p;
        rsum += p;
      }
      #pragma unroll
      for(int d = 1; d < 16; d <<= 1) rsum += __shfl_xor(rsum, d, 64);
      lsum[rr] += rsum;
    }
    // P -> wave-private LDS (bf16) to re-fragment for the PV MFMA A-operand
    #pragma unroll
    for(int js = 0; js < 4; js++)
      #pragma unroll
      for(int rr = 0; rr < 4; rr++)
        pw[swz(g * 4 + rr, js * 16 + lc)] = f2bf(sf[js][rr]);
    bf16x8 pa[2];
    #pragma unroll
    for(int kk = 0; kk < 2; kk++)
      pa[kk] = *(const bf16x8*)&pw[swz(lc, kk * 32 + g * 8)];
    #pragma unroll
    for(int ds = 0; ds < 4; ds++){
      #pragma unroll
      for(int kk = 0; kk < 2; kk++){
        bf16x8 vb = *(const bf16x8*)&lds_v[swz(ds * 16 + lc, kk * 32 + g * 8)];
        o[ds] = __builtin_amdgcn_mfma_f32_16x16x32_bf16(pa[kk], vb, o[ds], 0, 0, 0);
      }
    }
    __syncthreads();
  }
  // epilogue: normalize, add residual, write x1 (fp32)
  #pragma unroll
  for(int ds = 0; ds < 4; ds++)
    #pragma unroll
    for(int rr = 0; rr < 4; rr++){
      int ig = i0 + w * 16 + g * 4 + rr;
      int col = h * DH + ds * 16 + lc;
      size_t idx = (size_t)(b * TT + ig) * CC + col;
      x1[idx] = xln[idx] + o[ds][rr] / lsum[rr];
    }
}

// ---------------- host launcher ----------------
extern "C" void kernel_launch(void* const* d_in, const int* in_sizes, int n_in,
                              void* d_out, int out_size, void* d_ws, size_t ws_size,
                              hipStream_t stream){
  const float* x    = (const float*)d_in[0];
  const float* ln1g = (const float*)d_in[1];
  const float* ln1b = (const float*)d_in[2];
  const float* Wq   = (const float*)d_in[3];
  const float* bq   = (const float*)d_in[4];
  const float* Wk   = (const float*)d_in[5];
  const float* bk   = (const float*)d_in[6];
  const float* Wv   = (const float*)d_in[7];
  const float* bv   = (const float*)d_in[8];
  const float* ln2g = (const float*)d_in[9];
  const float* ln2b = (const float*)d_in[10];
  const float* W1   = (const float*)d_in[11];
  const float* b1   = (const float*)d_in[12];
  const float* W2   = (const float*)d_in[13];
  const float* b2   = (const float*)d_in[14];

  char* ws = (char*)d_ws;
  float*          xlnf = (float*)(ws + 0);            // 12582912 B
  unsigned short* xlnb = (unsigned short*)(ws + 12582912);  // 6291456
  float*          x1   = (float*)(ws + 18874368);     // 12582912
  unsigned short* hln2 = (unsigned short*)(ws + 31457280);  // 6291456
  unsigned short* wqkv = (unsigned short*)(ws + 37748736);  // 3538944
  float*          bqkv = (float*)(ws + 41287680);     // 9216
  unsigned short* w1t  = (unsigned short*)(ws + 41296896);  // 4718592
  unsigned short* w2t  = (unsigned short*)(ws + 46015488);  // 4718592
  unsigned short* qkv  = (unsigned short*)(ws + 50734080);  // 18874368
  unsigned short* vt   = (unsigned short*)(ws + 69608448);  // 6291456
  unsigned short* mlp1 = (unsigned short*)(ws + 50734080);  // 25165824 (aliases qkv+vt, dead by then)
  // total ws use: 75899904 B

  // weights -> bf16 B^T (N,K)
  transpose_convert<<<dim3(24, 24), 256, 0, stream>>>(Wq, wqkv,               CC, CC);
  transpose_convert<<<dim3(24, 24), 256, 0, stream>>>(Wk, wqkv + CC * CC,     CC, CC);
  transpose_convert<<<dim3(24, 24), 256, 0, stream>>>(Wv, wqkv + 2 * CC * CC, CC, CC);
  transpose_convert<<<dim3(96, 24), 256, 0, stream>>>(W1, w1t, CC, 4 * CC);      // (768,3072)->(3072,768)
  transpose_convert<<<dim3(24, 96), 256, 0, stream>>>(W2, w2t, 4 * CC, CC);      // (3072,768)->(768,3072)
  concat_bias<<<9, 256, 0, stream>>>(bq, bk, bv, bqkv);

  ln_kernel<<<NROWS, 256, 0, stream>>>(x, ln1g, ln1b, xlnf, xlnb);

  gemm_bt<0><<<dim3(18, 32), 256, 0, stream>>>(xlnb, wqkv, bqkv, nullptr, qkv, NROWS, 3 * CC, CC);

  transpose_v<<<dim3(TT / 64, BB * HH), 256, 0, stream>>>(qkv, vt);

  attn_kernel<<<dim3(TT / 64, BB * HH), 256, 0, stream>>>(qkv, vt, xlnf, x1);

  ln_kernel<<<NROWS, 256, 0, stream>>>(x1, ln2g, ln2b, nullptr, hln2);

  gemm_bt<1><<<dim3(24, 32), 256, 0, stream>>>(hln2, w1t, b1, nullptr, mlp1, NROWS, 4 * CC, CC);

  gemm_bt<2><<<dim3(6, 32), 256, 0, stream>>>(mlp1, w2t, b2, x1, d_out, NROWS, CC, 4 * CC);

  (void)in_sizes; (void)n_in; (void)out_size; (void)ws_size;
}

// Round 2
// 258.109 us; speedup vs baseline: 1.2408x; 1.2408x over previous
//
#include <hip/hip_runtime.h>
#include <cmath>

// Decoder block: LN1 -> QKV -> (swapped) causal attention -> residual -> LN2 -> MLP(GELU) -> residual
// B=2, T=2048, C=768, H=12, dh=64. All GEMMs bf16 MFMA 16x16x32, fp32 accumulate.

#define BB 2
#define TT 2048
#define CC 768
#define HH 12
#define DH 64
#define NROWS (BB*TT)   // 4096

typedef __attribute__((ext_vector_type(8))) short bf16x8;
typedef __attribute__((ext_vector_type(4))) float f32x4;
typedef __attribute__((ext_vector_type(4))) unsigned short u16x4;

__device__ __forceinline__ unsigned short f2bf(float f){
  union { float f; unsigned int i; } x; x.f = f;
  unsigned int u = x.i;
  return (unsigned short)((u + 0x7FFFu + ((u >> 16) & 1u)) >> 16);
}
// XOR-swizzle for [rows][64] bf16 LDS tiles (128B rows). Returns ELEMENT index.
__device__ __forceinline__ int swz(int r, int c){
  int b = (r << 7) + (c << 1);
  b ^= (r & 7) << 4;
  return b >> 1;
}
__device__ __forceinline__ float wred_sum(float v){
  #pragma unroll
  for(int m = 1; m < 64; m <<= 1) v += __shfl_xor(v, m, 64);
  return v;
}
__device__ __forceinline__ float gelu_exact(float x){
  return 0.5f * x * (1.0f + erff(x * 0.70710678118654752f));
}
// async global->LDS, 16B per lane; dest = ldsbase + lane*16 (wave-uniform base)
__device__ __forceinline__ void gload_lds16(const void* g, void* l){
  __builtin_amdgcn_global_load_lds((const __attribute__((address_space(1))) void*)g,
                                   (__attribute__((address_space(3))) void*)l, 16, 0, 0);
}

// ---------------- weight transpose+convert: in (K,N) f32 -> out (N,K) bf16 ----------------
__global__ __launch_bounds__(256) void transpose_convert(const float* __restrict__ in,
                                                         unsigned short* __restrict__ out,
                                                         int K, int N){
  __shared__ float tile[32][33];
  int n0 = blockIdx.x * 32, k0 = blockIdx.y * 32;
  int t = threadIdx.x; int c = t & 31; int r0 = t >> 5;
  #pragma unroll
  for(int p = 0; p < 4; p++){
    int r = r0 + p * 8;
    tile[r][c] = in[(size_t)(k0 + r) * N + n0 + c];
  }
  __syncthreads();
  #pragma unroll
  for(int p = 0; p < 4; p++){
    int r = r0 + p * 8;
    out[(size_t)(n0 + r) * K + k0 + c] = f2bf(tile[c][r]);
  }
}

__global__ __launch_bounds__(256) void concat_bias(const float* __restrict__ bq,
                                                   const float* __restrict__ bk,
                                                   const float* __restrict__ bv,
                                                   float* __restrict__ bqkv){
  int i = blockIdx.x * 256 + threadIdx.x;
  if(i < 3 * CC) bqkv[i] = (i < CC) ? bq[i] : (i < 2 * CC) ? bk[i - CC] : bv[i - 2 * CC];
}

// ---------------- LayerNorm (fp32 in, fp32+bf16 out), one block per row, C=768 ----------------
__global__ __launch_bounds__(256) void ln_kernel(const float* __restrict__ in,
                                                 const float* __restrict__ gm,
                                                 const float* __restrict__ bt,
                                                 float* __restrict__ out_f,
                                                 unsigned short* __restrict__ out_b){
  int r = blockIdx.x; int t = threadIdx.x;
  const float* row = in + (size_t)r * CC;
  float v0 = row[t], v1 = row[t + 256], v2 = row[t + 512];
  float s = wred_sum(v0 + v1 + v2);
  __shared__ float red[4];
  if((t & 63) == 0) red[t >> 6] = s;
  __syncthreads();
  float mu = (red[0] + red[1] + red[2] + red[3]) * (1.0f / CC);
  float d0 = v0 - mu, d1 = v1 - mu, d2 = v2 - mu;
  float q = wred_sum(d0 * d0 + d1 * d1 + d2 * d2);
  __shared__ float red2[4];
  if((t & 63) == 0) red2[t >> 6] = q;
  __syncthreads();
  float var = (red2[0] + red2[1] + red2[2] + red2[3]) * (1.0f / CC);
  float rinv = rsqrtf(var + 1e-3f);
  float o0 = d0 * rinv * gm[t]       + bt[t];
  float o1 = d1 * rinv * gm[t + 256] + bt[t + 256];
  float o2 = d2 * rinv * gm[t + 512] + bt[t + 512];
  size_t base = (size_t)r * CC;
  if(out_f){ out_f[base + t] = o0; out_f[base + t + 256] = o1; out_f[base + t + 512] = o2; }
  out_b[base + t] = f2bf(o0); out_b[base + t + 256] = f2bf(o1); out_b[base + t + 512] = f2bf(o2);
}

// ---------------- GEMM: C[M,N] = A[M,K](bf16) x Bt[N,K](bf16) + bias, 128x128 tile, BK=64 ----
// Staging via global_load_lds width=16: LINEAR LDS dest + inverse-swizzled per-lane SOURCE,
// swizzled ds_read (rule 21). MODE 0: +bias bf16 (QKV); 1: +bias GELU bf16 (MLP1); 2: +bias+resid f32.
template<int MODE>
__global__ __launch_bounds__(256) void gemm_bt(const unsigned short* __restrict__ A,
                                               const unsigned short* __restrict__ Bt,
                                               const float* __restrict__ bias,
                                               const float* __restrict__ resid,
                                               void* __restrict__ outp,
                                               int M, int N, int K){
  __shared__ unsigned short As[128 * 64];
  __shared__ unsigned short Bs[128 * 64];
  int m0 = blockIdx.y * 128, n0 = blockIdx.x * 128;
  int t = threadIdx.x; int w = t >> 6; int l = t & 63;
  int g = l >> 4; int lc = l & 15;
  int wm = w >> 1, wn = w & 1;
  f32x4 zero4 = {0.f, 0.f, 0.f, 0.f};
  f32x4 acc[4][4];
  #pragma unroll
  for(int mi = 0; mi < 4; mi++)
    #pragma unroll
    for(int ni = 0; ni < 4; ni++) acc[mi][ni] = zero4;

  for(int ks = 0; ks < K; ks += 64){
    // each wave: 4 calls x 1KB per operand; linear elem e -> (r, c_lin); src col = c_lin ^ ((r&7)<<3)
    #pragma unroll
    for(int p = 0; p < 4; p++){
      int e = (w * 4 + p) * 512 + l * 8;
      int r = e >> 6, clin = e & 63;
      int csrc = clin ^ ((r & 7) << 3);
      gload_lds16(A  + (size_t)(m0 + r) * K + ks + csrc, &As[(w * 4 + p) * 512]);
      gload_lds16(Bt + (size_t)(n0 + r) * K + ks + csrc, &Bs[(w * 4 + p) * 512]);
    }
    __syncthreads();
    #pragma unroll
    for(int kk = 0; kk < 2; kk++){
      bf16x8 af[4], bfv[4];
      #pragma unroll
      for(int mi = 0; mi < 4; mi++) af[mi]  = *(const bf16x8*)&As[swz(wm * 64 + mi * 16 + lc, kk * 32 + g * 8)];
      #pragma unroll
      for(int ni = 0; ni < 4; ni++) bfv[ni] = *(const bf16x8*)&Bs[swz(wn * 64 + ni * 16 + lc, kk * 32 + g * 8)];
      #pragma unroll
      for(int mi = 0; mi < 4; mi++)
        #pragma unroll
        for(int ni = 0; ni < 4; ni++)
          acc[mi][ni] = __builtin_amdgcn_mfma_f32_16x16x32_bf16(af[mi], bfv[ni], acc[mi][ni], 0, 0, 0);
    }
    __syncthreads();
  }
  #pragma unroll
  for(int mi = 0; mi < 4; mi++)
    #pragma unroll
    for(int ni = 0; ni < 4; ni++){
      int col = n0 + wn * 64 + ni * 16 + lc;
      float bvv = bias[col];
      #pragma unroll
      for(int rr = 0; rr < 4; rr++){
        int row = m0 + wm * 64 + mi * 16 + g * 4 + rr;
        float v = acc[mi][ni][rr] + bvv;
        size_t idx = (size_t)row * N + col;
        if(MODE == 1) v = gelu_exact(v);
        if(MODE == 2) ((float*)outp)[idx] = v + resid[idx];
        else          ((unsigned short*)outp)[idx] = f2bf(v);
      }
    }
}

// ---------------- V transpose: qkv v-part (B,T,H,dh) -> vt (B,H,dh,T) ----------------
__global__ __launch_bounds__(256) void transpose_v(const unsigned short* __restrict__ qkv,
                                                   unsigned short* __restrict__ vt){
  __shared__ unsigned short tile[64][65];
  int t0 = blockIdx.x * 64; int bh = blockIdx.y;
  int b = bh / HH, h = bh % HH;
  int t = threadIdx.x;
  #pragma unroll
  for(int p = 0; p < 2; p++){
    int idx = p * 256 + t; int r = idx >> 3; int c = (idx & 7) * 8;
    bf16x8 v = *(const bf16x8*)(qkv + (size_t)(b * TT + t0 + r) * (3 * CC) + 2 * CC + h * DH + c);
    #pragma unroll
    for(int e = 0; e < 8; e++) tile[r][c + e] = (unsigned short)v[e];
  }
  __syncthreads();
  #pragma unroll
  for(int p = 0; p < 2; p++){
    int idx = p * 256 + t; int d = idx >> 3; int c = (idx & 7) * 8;
    bf16x8 v;
    #pragma unroll
    for(int e = 0; e < 8; e++) v[e] = (short)tile[c + e][d];
    *(bf16x8*)(vt + (size_t)(bh * DH + d) * TT + t0 + c) = v;
  }
}

// ---------------- Flash attention v2: wave-independent, swapped QK^T, balanced pairing ----
// Reference semantics: score[i,j] = k_i . q_j, mask j<=i, softmax over j.
// Swapped MFMA: S^T = mfma(A=q rows j, B=k cols i) -> lane (g,lc) holds S[i=lc][j=js*16+g*4+rr].
// Softmax over j: 15 in-reg + 2 shfl_xor (g-axis). Each wave owns a 16-row i-tile,
// processes pair (pp, 127-pp) for uniform cost (~33 j-tiles). No block barriers.
__global__ __launch_bounds__(128) void attn_kernel(const unsigned short* __restrict__ qkv,
                                                   const unsigned short* __restrict__ vt,
                                                   const float* __restrict__ xln,
                                                   float* __restrict__ x1){
  __shared__ unsigned short lds_p[2 * 16 * 64]; // per-wave 16x64 swizzled P tile
  int bh = blockIdx.y; int b = bh / HH, h = bh % HH;
  int t = threadIdx.x; int w = t >> 6; int l = t & 63;
  int g = l >> 4, lc = l & 15;
  unsigned short* pw = lds_p + w * 1024;
  int pp = blockIdx.x * 2 + w;   // 0..63
  const float SC = 0.125f * 1.44269504f;  // score scale in log2 domain
  const float THR = 11.5f;                // defer-max threshold (~e^8)

  for(int half = 0; half < 2; half++){
    int i16 = half ? (127 - pp) : pp;
    int i0w = i16 * 16;
    int irow = i0w + lc;  // this lane's i (softmax state index)
    // B-operand: k rows i (per-wave resident)
    bf16x8 bk[2];
    #pragma unroll
    for(int kk = 0; kk < 2; kk++)
      bk[kk] = *(const bf16x8*)(qkv + (size_t)(b * TT + irow) * (3 * CC) + CC + h * DH + kk * 32 + g * 8);

    float m_ = -1e30f, lsum = 0.f;
    f32x4 zero4 = {0.f, 0.f, 0.f, 0.f};
    f32x4 o[4];
    #pragma unroll
    for(int ds = 0; ds < 4; ds++) o[ds] = zero4;

    int NJT = (i0w + 16 + 63) >> 6;
    // prefetch q A-frags for jt=0
    bf16x8 aq[8];
    #pragma unroll
    for(int js = 0; js < 4; js++)
      #pragma unroll
      for(int kk = 0; kk < 2; kk++)
        aq[js * 2 + kk] = *(const bf16x8*)(qkv + (size_t)(b * TT + js * 16 + lc) * (3 * CC) + h * DH + kk * 32 + g * 8);

    for(int jt = 0; jt < NJT; jt++){
      int j0 = jt * 64;
      // QK^T (swapped): S^T[j][i]
      f32x4 s[4];
      #pragma unroll
      for(int js = 0; js < 4; js++){
        s[js] = zero4;
        #pragma unroll
        for(int kk = 0; kk < 2; kk++)
          s[js] = __builtin_amdgcn_mfma_f32_16x16x32_bf16(aq[js * 2 + kk], bk[kk], s[js], 0, 0, 0);
      }
      // prefetch next tile's q frags (latency hidden under softmax+PV)
      bf16x8 aqn[8];
      if(jt + 1 < NJT){
        #pragma unroll
        for(int js = 0; js < 4; js++)
          #pragma unroll
          for(int kk = 0; kk < 2; kk++)
            aqn[js * 2 + kk] = *(const bf16x8*)(qkv + (size_t)(b * TT + j0 + 64 + js * 16 + lc) * (3 * CC) + h * DH + kk * 32 + g * 8);
      }
      // issue V^T B-frag loads now (waited at PV mfma, hidden under softmax)
      bf16x8 vb[8];
      #pragma unroll
      for(int ds = 0; ds < 4; ds++)
        #pragma unroll
        for(int kk = 0; kk < 2; kk++)
          vb[ds * 2 + kk] = *(const bf16x8*)(vt + (size_t)(bh * DH + ds * 16 + lc) * TT + j0 + kk * 32 + g * 8);

      // scale + causal mask + tile max (in log2 domain)
      float mx = -1e30f;
      #pragma unroll
      for(int js = 0; js < 4; js++)
        #pragma unroll
        for(int rr = 0; rr < 4; rr++){
          int j = j0 + js * 16 + g * 4 + rr;
          float sv = s[js][rr] * SC;
          sv = (j <= irow) ? sv : -1e30f;
          s[js][rr] = sv;
          mx = fmaxf(mx, sv);
        }
      mx = fmaxf(mx, __shfl_xor(mx, 16, 64));
      mx = fmaxf(mx, __shfl_xor(mx, 32, 64));
      // defer-max: rescale only when the running max grew materially
      if(__any(mx > m_ + THR)){
        float mn = fmaxf(m_, mx);
        float al = exp2f(m_ - mn);
        m_ = mn;
        lsum *= al;
        #pragma unroll
        for(int rr = 0; rr < 4; rr++){
          float alb = __shfl(al, g * 4 + rr, 64);
          #pragma unroll
          for(int ds = 0; ds < 4; ds++) o[ds][rr] *= alb;
        }
      }
      float rsum = 0.f;
      #pragma unroll
      for(int js = 0; js < 4; js++)
        #pragma unroll
        for(int rr = 0; rr < 4; rr++){
          float pv = exp2f(s[js][rr] - m_);
          s[js][rr] = pv;
          rsum += pv;
        }
      rsum += __shfl_xor(rsum, 16, 64);
      rsum += __shfl_xor(rsum, 32, 64);
      lsum += rsum;
      // P -> wave-private LDS (pw[i=lc][j], swizzled), 4x ds_write_b64
      #pragma unroll
      for(int js = 0; js < 4; js++){
        u16x4 pk;
        #pragma unroll
        for(int rr = 0; rr < 4; rr++) pk[rr] = f2bf(s[js][rr]);
        *(u16x4*)&pw[swz(lc, js * 16 + g * 4)] = pk;
      }
      // P A-frags + PV
      bf16x8 pa[2];
      #pragma unroll
      for(int kk = 0; kk < 2; kk++)
        pa[kk] = *(const bf16x8*)&pw[swz(lc, kk * 32 + g * 8)];
      #pragma unroll
      for(int ds = 0; ds < 4; ds++)
        #pragma unroll
        for(int kk = 0; kk < 2; kk++)
          o[ds] = __builtin_amdgcn_mfma_f32_16x16x32_bf16(pa[kk], vb[ds * 2 + kk], o[ds], 0, 0, 0);
      if(jt + 1 < NJT){
        #pragma unroll
        for(int q = 0; q < 8; q++) aq[q] = aqn[q];
      }
    }
    // epilogue: o rows i = g*4+rr, cols d = ds*16+lc; lsum lives at lane lc=i
    #pragma unroll
    for(int rr = 0; rr < 4; rr++){
      float lsb = __shfl(lsum, g * 4 + rr, 64);
      float rinv = 1.0f / lsb;
      int ig = i0w + g * 4 + rr;
      #pragma unroll
      for(int ds = 0; ds < 4; ds++){
        int col = h * DH + ds * 16 + lc;
        size_t idx = (size_t)(b * TT + ig) * CC + col;
        x1[idx] = xln[idx] + o[ds][rr] * rinv;
      }
    }
  }
}

// ---------------- host launcher ----------------
extern "C" void kernel_launch(void* const* d_in, const int* in_sizes, int n_in,
                              void* d_out, int out_size, void* d_ws, size_t ws_size,
                              hipStream_t stream){
  const float* x    = (const float*)d_in[0];
  const float* ln1g = (const float*)d_in[1];
  const float* ln1b = (const float*)d_in[2];
  const float* Wq   = (const float*)d_in[3];
  const float* bq   = (const float*)d_in[4];
  const float* Wk   = (const float*)d_in[5];
  const float* bk   = (const float*)d_in[6];
  const float* Wv   = (const float*)d_in[7];
  const float* bv   = (const float*)d_in[8];
  const float* ln2g = (const float*)d_in[9];
  const float* ln2b = (const float*)d_in[10];
  const float* W1   = (const float*)d_in[11];
  const float* b1   = (const float*)d_in[12];
  const float* W2   = (const float*)d_in[13];
  const float* b2   = (const float*)d_in[14];

  char* ws = (char*)d_ws;
  float*          xlnf = (float*)(ws + 0);                  // 12582912 B
  unsigned short* xlnb = (unsigned short*)(ws + 12582912);  // 6291456
  float*          x1   = (float*)(ws + 18874368);           // 12582912
  unsigned short* hln2 = (unsigned short*)(ws + 31457280);  // 6291456
  unsigned short* wqkv = (unsigned short*)(ws + 37748736);  // 3538944
  float*          bqkv = (float*)(ws + 41287680);           // 9216
  unsigned short* w1t  = (unsigned short*)(ws + 41296896);  // 4718592
  unsigned short* w2t  = (unsigned short*)(ws + 46015488);  // 4718592
  unsigned short* qkv  = (unsigned short*)(ws + 50734080);  // 18874368
  unsigned short* vt   = (unsigned short*)(ws + 69608448);  // 6291456
  unsigned short* mlp1 = (unsigned short*)(ws + 50734080);  // aliases qkv+vt (dead by then)

  transpose_convert<<<dim3(24, 24), 256, 0, stream>>>(Wq, wqkv,               CC, CC);
  transpose_convert<<<dim3(24, 24), 256, 0, stream>>>(Wk, wqkv + CC * CC,     CC, CC);
  transpose_convert<<<dim3(24, 24), 256, 0, stream>>>(Wv, wqkv + 2 * CC * CC, CC, CC);
  transpose_convert<<<dim3(96, 24), 256, 0, stream>>>(W1, w1t, CC, 4 * CC);
  transpose_convert<<<dim3(24, 96), 256, 0, stream>>>(W2, w2t, 4 * CC, CC);
  concat_bias<<<9, 256, 0, stream>>>(bq, bk, bv, bqkv);

  ln_kernel<<<NROWS, 256, 0, stream>>>(x, ln1g, ln1b, xlnf, xlnb);

  gemm_bt<0><<<dim3(18, 32), 256, 0, stream>>>(xlnb, wqkv, bqkv, nullptr, qkv, NROWS, 3 * CC, CC);

  transpose_v<<<dim3(TT / 64, BB * HH), 256, 0, stream>>>(qkv, vt);

  attn_kernel<<<dim3(32, BB * HH), 128, 0, stream>>>(qkv, vt, xlnf, x1);

  ln_kernel<<<NROWS, 256, 0, stream>>>(x1, ln2g, ln2b, nullptr, hln2);

  gemm_bt<1><<<dim3(24, 32), 256, 0, stream>>>(hln2, w1t, b1, nullptr, mlp1, NROWS, 4 * CC, CC);

  gemm_bt<2><<<dim3(6, 32), 256, 0, stream>>>(mlp1, w2t, b2, x1, d_out, NROWS, CC, 4 * CC);

  (void)in_sizes; (void)n_in; (void)out_size; (void)ws_size;
}

// Round 3
// 220.949 us; speedup vs baseline: 1.4494x; 1.1682x over previous
//
#include <hip/hip_runtime.h>
#include <cmath>

// Decoder block: LN1 -> QKV -> (swapped) causal attention -> residual -> LN2 -> MLP(GELU) -> residual
// B=2, T=2048, C=768, H=12, dh=64. All GEMMs bf16 MFMA 16x16x32, fp32 accumulate.

#define BB 2
#define TT 2048
#define CC 768
#define HH 12
#define DH 64
#define NROWS (BB*TT)   // 4096

typedef __attribute__((ext_vector_type(8))) short bf16x8;
typedef __attribute__((ext_vector_type(4))) float f32x4;
typedef __attribute__((ext_vector_type(4))) unsigned short u16x4;

__device__ __forceinline__ unsigned short f2bf(float f){
  union { float f; unsigned int i; } x; x.f = f;
  unsigned int u = x.i;
  return (unsigned short)((u + 0x7FFFu + ((u >> 16) & 1u)) >> 16);
}
// XOR-swizzle for [rows][64] bf16 LDS tiles (128B rows). Returns ELEMENT index.
__device__ __forceinline__ int swz(int r, int c){
  int b = (r << 7) + (c << 1);
  b ^= (r & 7) << 4;
  return b >> 1;
}
__device__ __forceinline__ float wred_sum(float v){
  #pragma unroll
  for(int m = 1; m < 64; m <<= 1) v += __shfl_xor(v, m, 64);
  return v;
}
__device__ __forceinline__ float gelu_exact(float x){
  return 0.5f * x * (1.0f + erff(x * 0.70710678118654752f));
}
// async global->LDS, 16B per lane; dest = wave-uniform base + lane*16
__device__ __forceinline__ void gload_lds16(const void* g, void* l){
  __builtin_amdgcn_global_load_lds((const __attribute__((address_space(1))) void*)g,
                                   (__attribute__((address_space(3))) void*)l, 16, 0, 0);
}

// ---------------- weight transpose+convert: in (K,N) f32 -> out (N,K) bf16 ----------------
__global__ __launch_bounds__(256) void transpose_convert(const float* __restrict__ in,
                                                         unsigned short* __restrict__ out,
                                                         int K, int N){
  __shared__ float tile[32][33];
  int n0 = blockIdx.x * 32, k0 = blockIdx.y * 32;
  int t = threadIdx.x; int c = t & 31; int r0 = t >> 5;
  #pragma unroll
  for(int p = 0; p < 4; p++){
    int r = r0 + p * 8;
    tile[r][c] = in[(size_t)(k0 + r) * N + n0 + c];
  }
  __syncthreads();
  #pragma unroll
  for(int p = 0; p < 4; p++){
    int r = r0 + p * 8;
    out[(size_t)(n0 + r) * K + k0 + c] = f2bf(tile[c][r]);
  }
}

__global__ __launch_bounds__(256) void concat_bias(const float* __restrict__ bq,
                                                   const float* __restrict__ bk,
                                                   const float* __restrict__ bv,
                                                   float* __restrict__ bqkv){
  int i = blockIdx.x * 256 + threadIdx.x;
  if(i < 3 * CC) bqkv[i] = (i < CC) ? bq[i] : (i < 2 * CC) ? bk[i - CC] : bv[i - 2 * CC];
}

// ---------------- LayerNorm (fp32 in, fp32+bf16 out), one block per row, C=768 ----------------
__global__ __launch_bounds__(256) void ln_kernel(const float* __restrict__ in,
                                                 const float* __restrict__ gm,
                                                 const float* __restrict__ bt,
                                                 float* __restrict__ out_f,
                                                 unsigned short* __restrict__ out_b){
  int r = blockIdx.x; int t = threadIdx.x;
  const float* row = in + (size_t)r * CC;
  float v0 = row[t], v1 = row[t + 256], v2 = row[t + 512];
  float s = wred_sum(v0 + v1 + v2);
  __shared__ float red[4];
  if((t & 63) == 0) red[t >> 6] = s;
  __syncthreads();
  float mu = (red[0] + red[1] + red[2] + red[3]) * (1.0f / CC);
  float d0 = v0 - mu, d1 = v1 - mu, d2 = v2 - mu;
  float q = wred_sum(d0 * d0 + d1 * d1 + d2 * d2);
  __shared__ float red2[4];
  if((t & 63) == 0) red2[t >> 6] = q;
  __syncthreads();
  float var = (red2[0] + red2[1] + red2[2] + red2[3]) * (1.0f / CC);
  float rinv = rsqrtf(var + 1e-3f);
  float o0 = d0 * rinv * gm[t]       + bt[t];
  float o1 = d1 * rinv * gm[t + 256] + bt[t + 256];
  float o2 = d2 * rinv * gm[t + 512] + bt[t + 512];
  size_t base = (size_t)r * CC;
  if(out_f){ out_f[base + t] = o0; out_f[base + t + 256] = o1; out_f[base + t + 512] = o2; }
  out_b[base + t] = f2bf(o0); out_b[base + t + 256] = f2bf(o1); out_b[base + t + 512] = f2bf(o2);
}

// ---------------- GEMM: C[M,N] = A[M,K](bf16) x Bt[N,K](bf16) + bias, 128x128 tile, BK=64 ----
template<int MODE>
__global__ __launch_bounds__(256) void gemm_bt(const unsigned short* __restrict__ A,
                                               const unsigned short* __restrict__ Bt,
                                               const float* __restrict__ bias,
                                               const float* __restrict__ resid,
                                               void* __restrict__ outp,
                                               int M, int N, int K){
  __shared__ unsigned short As[128 * 64];
  __shared__ unsigned short Bs[128 * 64];
  int m0 = blockIdx.y * 128, n0 = blockIdx.x * 128;
  int t = threadIdx.x; int w = t >> 6; int l = t & 63;
  int g = l >> 4; int lc = l & 15;
  int wm = w >> 1, wn = w & 1;
  f32x4 zero4 = {0.f, 0.f, 0.f, 0.f};
  f32x4 acc[4][4];
  #pragma unroll
  for(int mi = 0; mi < 4; mi++)
    #pragma unroll
    for(int ni = 0; ni < 4; ni++) acc[mi][ni] = zero4;

  for(int ks = 0; ks < K; ks += 64){
    #pragma unroll
    for(int p = 0; p < 4; p++){
      int e = (w * 4 + p) * 512 + l * 8;
      int r = e >> 6, clin = e & 63;
      int csrc = clin ^ ((r & 7) << 3);
      gload_lds16(A  + (size_t)(m0 + r) * K + ks + csrc, &As[(w * 4 + p) * 512]);
      gload_lds16(Bt + (size_t)(n0 + r) * K + ks + csrc, &Bs[(w * 4 + p) * 512]);
    }
    __syncthreads();
    #pragma unroll
    for(int kk = 0; kk < 2; kk++){
      bf16x8 af[4], bfv[4];
      #pragma unroll
      for(int mi = 0; mi < 4; mi++) af[mi]  = *(const bf16x8*)&As[swz(wm * 64 + mi * 16 + lc, kk * 32 + g * 8)];
      #pragma unroll
      for(int ni = 0; ni < 4; ni++) bfv[ni] = *(const bf16x8*)&Bs[swz(wn * 64 + ni * 16 + lc, kk * 32 + g * 8)];
      #pragma unroll
      for(int mi = 0; mi < 4; mi++)
        #pragma unroll
        for(int ni = 0; ni < 4; ni++)
          acc[mi][ni] = __builtin_amdgcn_mfma_f32_16x16x32_bf16(af[mi], bfv[ni], acc[mi][ni], 0, 0, 0);
    }
    __syncthreads();
  }
  #pragma unroll
  for(int mi = 0; mi < 4; mi++)
    #pragma unroll
    for(int ni = 0; ni < 4; ni++){
      int col = n0 + wn * 64 + ni * 16 + lc;
      float bvv = bias[col];
      #pragma unroll
      for(int rr = 0; rr < 4; rr++){
        int row = m0 + wm * 64 + mi * 16 + g * 4 + rr;
        float v = acc[mi][ni][rr] + bvv;
        size_t idx = (size_t)row * N + col;
        if(MODE == 1) v = gelu_exact(v);
        if(MODE == 2) ((float*)outp)[idx] = v + resid[idx];
        else          ((unsigned short*)outp)[idx] = f2bf(v);
      }
    }
}

// ---------------- V transpose: qkv v-part (B,T,H,dh) -> vt (B,H,dh,T) ----------------
__global__ __launch_bounds__(256) void transpose_v(const unsigned short* __restrict__ qkv,
                                                   unsigned short* __restrict__ vt){
  __shared__ unsigned short tile[64][65];
  int t0 = blockIdx.x * 64; int bh = blockIdx.y;
  int b = bh / HH, h = bh % HH;
  int t = threadIdx.x;
  #pragma unroll
  for(int p = 0; p < 2; p++){
    int idx = p * 256 + t; int r = idx >> 3; int c = (idx & 7) * 8;
    bf16x8 v = *(const bf16x8*)(qkv + (size_t)(b * TT + t0 + r) * (3 * CC) + 2 * CC + h * DH + c);
    #pragma unroll
    for(int e = 0; e < 8; e++) tile[r][c + e] = (unsigned short)v[e];
  }
  __syncthreads();
  #pragma unroll
  for(int p = 0; p < 2; p++){
    int idx = p * 256 + t; int d = idx >> 3; int c = (idx & 7) * 8;
    bf16x8 v;
    #pragma unroll
    for(int e = 0; e < 8; e++) v[e] = (short)tile[c + e][d];
    *(bf16x8*)(vt + (size_t)(bh * DH + d) * TT + t0 + c) = v;
  }
}

// ---------------- Flash attention v3: 8-wave blocks, LDS-shared q/V staging ----
// Reference semantics: score[i,j] = k_i . q_j, mask j<=i, softmax over j.
// Block handles rows [bx*128, bx*128+128): wave w owns i-tile bx*8+w (16 rows).
// Per j-tile: q rows j and v^T rows d staged once into LDS (global_load_lds,
// inverse-swizzled source), shared by all 8 waves; double-buffered, 1 barrier/tile.
// Block mapping: xcd=o&7, q=o>>3 -> head=xcd*3+q%3, bx=15-q/3 (same-head blocks
// share an XCD L2; heaviest blocks dispatch first).
__global__ __launch_bounds__(512) void attn_kernel(const unsigned short* __restrict__ qkv,
                                                   const unsigned short* __restrict__ vt,
                                                   const float* __restrict__ xln,
                                                   float* __restrict__ x1){
  __shared__ unsigned short Aq[2][64 * 64];
  __shared__ unsigned short Vs[2][64 * 64];
  __shared__ unsigned short Ps[8][16 * 64];
  int o = blockIdx.x;
  int xcd = o & 7, qq = o >> 3;          // qq 0..47
  int head = xcd * 3 + (qq % 3);         // 0..23
  int bx = 15 - qq / 3;                  // 15..0 (heavy first)
  int b = head / HH, h = head % HH;
  int t = threadIdx.x; int w = t >> 6; int l = t & 63;
  int g = l >> 4, lc = l & 15;
  int i0w = bx * 128 + w * 16;
  int irow = i0w + lc;
  unsigned short* pw = &Ps[w][0];
  const float SC = 0.125f * 1.44269504f;  // score scale in log2 domain
  const float THR = 11.5f;                // defer-max threshold (~e^8)

  // staging geometry: thread t covers tile row r_st, cols c0..c0+7 (linear dest)
  int r_st = t >> 3;
  int c0 = (t & 7) * 8;
  int csrc = c0 ^ ((r_st & 7) << 3);     // inverse-swizzled source column

  // B-operand: k rows i (per-wave resident)
  bf16x8 bk[2];
  #pragma unroll
  for(int kk = 0; kk < 2; kk++)
    bk[kk] = *(const bf16x8*)(qkv + (size_t)(b * TT + irow) * (3 * CC) + CC + h * DH + kk * 32 + g * 8);

  float m_ = -1e30f, lsum = 0.f;
  f32x4 zero4 = {0.f, 0.f, 0.f, 0.f};
  f32x4 o4[4];
  #pragma unroll
  for(int ds = 0; ds < 4; ds++) o4[ds] = zero4;

  int NJT_w = (i0w + 16 + 63) >> 6;      // this wave's causal j-tile count
  int NJTmax = 2 * bx + 2;               // block-wide j-tile count

  // stage jt=0
  gload_lds16(qkv + (size_t)(b * TT + 0 + r_st) * (3 * CC) + h * DH + csrc, &Aq[0][w * 512]);
  gload_lds16(vt  + (size_t)(head * DH + r_st) * TT + 0 + csrc,             &Vs[0][w * 512]);
  __syncthreads();

  int buf = 0;
  for(int jt = 0; jt < NJTmax; jt++){
    int j0 = jt * 64;
    if(jt + 1 < NJTmax){
      int j1 = j0 + 64;
      gload_lds16(qkv + (size_t)(b * TT + j1 + r_st) * (3 * CC) + h * DH + csrc, &Aq[buf ^ 1][w * 512]);
      gload_lds16(vt  + (size_t)(head * DH + r_st) * TT + j1 + csrc,             &Vs[buf ^ 1][w * 512]);
    }
    if(jt < NJT_w){
      // QK^T (swapped): S^T[j][i]; A = q rows j (from LDS), B = k rows i (reg)
      f32x4 s[4];
      #pragma unroll
      for(int js = 0; js < 4; js++){
        s[js] = zero4;
        #pragma unroll
        for(int kk = 0; kk < 2; kk++){
          bf16x8 aq = *(const bf16x8*)&Aq[buf][swz(js * 16 + lc, kk * 32 + g * 8)];
          s[js] = __builtin_amdgcn_mfma_f32_16x16x32_bf16(aq, bk[kk], s[js], 0, 0, 0);
        }
      }
      // scale + causal mask + tile max (log2 domain)
      float mx = -1e30f;
      #pragma unroll
      for(int js = 0; js < 4; js++)
        #pragma unroll
        for(int rr = 0; rr < 4; rr++){
          int j = j0 + js * 16 + g * 4 + rr;
          float sv = s[js][rr] * SC;
          sv = (j <= irow) ? sv : -1e30f;
          s[js][rr] = sv;
          mx = fmaxf(mx, sv);
        }
      mx = fmaxf(mx, __shfl_xor(mx, 16, 64));
      mx = fmaxf(mx, __shfl_xor(mx, 32, 64));
      if(__any(mx > m_ + THR)){
        float mn = fmaxf(m_, mx);
        float al = exp2f(m_ - mn);
        m_ = mn;
        lsum *= al;
        #pragma unroll
        for(int rr = 0; rr < 4; rr++){
          float alb = __shfl(al, g * 4 + rr, 64);
          #pragma unroll
          for(int ds = 0; ds < 4; ds++) o4[ds][rr] *= alb;
        }
      }
      float rsum = 0.f;
      #pragma unroll
      for(int js = 0; js < 4; js++)
        #pragma unroll
        for(int rr = 0; rr < 4; rr++){
          float pv = exp2f(s[js][rr] - m_);
          s[js][rr] = pv;
          rsum += pv;
        }
      rsum += __shfl_xor(rsum, 16, 64);
      rsum += __shfl_xor(rsum, 32, 64);
      lsum += rsum;
      // P -> wave-private LDS (pw[i=lc][j], swizzled)
      #pragma unroll
      for(int js = 0; js < 4; js++){
        u16x4 pk;
        #pragma unroll
        for(int rr = 0; rr < 4; rr++) pk[rr] = f2bf(s[js][rr]);
        *(u16x4*)&pw[swz(lc, js * 16 + g * 4)] = pk;
      }
      bf16x8 pa[2];
      #pragma unroll
      for(int kk = 0; kk < 2; kk++)
        pa[kk] = *(const bf16x8*)&pw[swz(lc, kk * 32 + g * 8)];
      #pragma unroll
      for(int ds = 0; ds < 4; ds++)
        #pragma unroll
        for(int kk = 0; kk < 2; kk++){
          bf16x8 vb = *(const bf16x8*)&Vs[buf][swz(ds * 16 + lc, kk * 32 + g * 8)];
          o4[ds] = __builtin_amdgcn_mfma_f32_16x16x32_bf16(pa[kk], vb, o4[ds], 0, 0, 0);
        }
    }
    __syncthreads();
    buf ^= 1;
  }
  // epilogue: o rows i = g*4+rr, cols d = ds*16+lc; softmax state lives at lane lc=i
  #pragma unroll
  for(int rr = 0; rr < 4; rr++){
    float lsb = __shfl(lsum, g * 4 + rr, 64);
    float rinv = 1.0f / lsb;
    int ig = i0w + g * 4 + rr;
    #pragma unroll
    for(int ds = 0; ds < 4; ds++){
      int col = h * DH + ds * 16 + lc;
      size_t idx = (size_t)(b * TT + ig) * CC + col;
      x1[idx] = xln[idx] + o4[ds][rr] * rinv;
    }
  }
}

// ---------------- host launcher ----------------
extern "C" void kernel_launch(void* const* d_in, const int* in_sizes, int n_in,
                              void* d_out, int out_size, void* d_ws, size_t ws_size,
                              hipStream_t stream){
  const float* x    = (const float*)d_in[0];
  const float* ln1g = (const float*)d_in[1];
  const float* ln1b = (const float*)d_in[2];
  const float* Wq   = (const float*)d_in[3];
  const float* bq   = (const float*)d_in[4];
  const float* Wk   = (const float*)d_in[5];
  const float* bk   = (const float*)d_in[6];
  const float* Wv   = (const float*)d_in[7];
  const float* bv   = (const float*)d_in[8];
  const float* ln2g = (const float*)d_in[9];
  const float* ln2b = (const float*)d_in[10];
  const float* W1   = (const float*)d_in[11];
  const float* b1   = (const float*)d_in[12];
  const float* W2   = (const float*)d_in[13];
  const float* b2   = (const float*)d_in[14];

  char* ws = (char*)d_ws;
  float*          xlnf = (float*)(ws + 0);                  // 12582912 B
  unsigned short* xlnb = (unsigned short*)(ws + 12582912);  // 6291456
  float*          x1   = (float*)(ws + 18874368);           // 12582912
  unsigned short* hln2 = (unsigned short*)(ws + 31457280);  // 6291456
  unsigned short* wqkv = (unsigned short*)(ws + 37748736);  // 3538944
  float*          bqkv = (float*)(ws + 41287680);           // 9216
  unsigned short* w1t  = (unsigned short*)(ws + 41296896);  // 4718592
  unsigned short* w2t  = (unsigned short*)(ws + 46015488);  // 4718592
  unsigned short* qkv  = (unsigned short*)(ws + 50734080);  // 18874368
  unsigned short* vt   = (unsigned short*)(ws + 69608448);  // 6291456
  unsigned short* mlp1 = (unsigned short*)(ws + 50734080);  // aliases qkv+vt (dead by then)

  transpose_convert<<<dim3(24, 24), 256, 0, stream>>>(Wq, wqkv,               CC, CC);
  transpose_convert<<<dim3(24, 24), 256, 0, stream>>>(Wk, wqkv + CC * CC,     CC, CC);
  transpose_convert<<<dim3(24, 24), 256, 0, stream>>>(Wv, wqkv + 2 * CC * CC, CC, CC);
  transpose_convert<<<dim3(96, 24), 256, 0, stream>>>(W1, w1t, CC, 4 * CC);
  transpose_convert<<<dim3(24, 96), 256, 0, stream>>>(W2, w2t, 4 * CC, CC);
  concat_bias<<<9, 256, 0, stream>>>(bq, bk, bv, bqkv);

  ln_kernel<<<NROWS, 256, 0, stream>>>(x, ln1g, ln1b, xlnf, xlnb);

  gemm_bt<0><<<dim3(18, 32), 256, 0, stream>>>(xlnb, wqkv, bqkv, nullptr, qkv, NROWS, 3 * CC, CC);

  transpose_v<<<dim3(TT / 64, BB * HH), 256, 0, stream>>>(qkv, vt);

  attn_kernel<<<dim3(384), 512, 0, stream>>>(qkv, vt, xlnf, x1);

  ln_kernel<<<NROWS, 256, 0, stream>>>(x1, ln2g, ln2b, nullptr, hln2);

  gemm_bt<1><<<dim3(24, 32), 256, 0, stream>>>(hln2, w1t, b1, nullptr, mlp1, NROWS, 4 * CC, CC);

  gemm_bt<2><<<dim3(6, 32), 256, 0, stream>>>(mlp1, w2t, b2, x1, d_out, NROWS, CC, 4 * CC);

  (void)in_sizes; (void)n_in; (void)out_size; (void)ws_size;
}

// Round 4
// 200.932 us; speedup vs baseline: 1.5938x; 1.0996x over previous
//
#include <hip/hip_runtime.h>
#include <cmath>

// Decoder block: LN1 -> QKV -> (swapped) causal attention -> residual -> LN2 -> MLP(GELU) -> residual
// B=2, T=2048, C=768, H=12, dh=64. All GEMMs bf16 MFMA 16x16x32, fp32 accumulate.

#define BB 2
#define TT 2048
#define CC 768
#define HH 12
#define DH 64
#define NROWS (BB*TT)   // 4096

typedef __attribute__((ext_vector_type(8))) short bf16x8;
typedef __attribute__((ext_vector_type(4))) float f32x4;
typedef __attribute__((ext_vector_type(4))) unsigned short u16x4;

__device__ __forceinline__ unsigned short f2bf(float f){
  union { float f; unsigned int i; } x; x.f = f;
  unsigned int u = x.i;
  return (unsigned short)((u + 0x7FFFu + ((u >> 16) & 1u)) >> 16);
}
// XOR-swizzle for [rows][64] bf16 LDS tiles (128B rows). Returns ELEMENT index.
__device__ __forceinline__ int swz(int r, int c){
  int b = (r << 7) + (c << 1);
  b ^= (r & 7) << 4;
  return b >> 1;
}
__device__ __forceinline__ float wred_sum(float v){
  #pragma unroll
  for(int m = 1; m < 64; m <<= 1) v += __shfl_xor(v, m, 64);
  return v;
}
__device__ __forceinline__ float gelu_exact(float x){
  return 0.5f * x * (1.0f + erff(x * 0.70710678118654752f));
}
// async global->LDS, 16B per lane; dest = wave-uniform base + lane*16
__device__ __forceinline__ void gload_lds16(const void* g, void* l){
  __builtin_amdgcn_global_load_lds((const __attribute__((address_space(1))) void*)g,
                                   (__attribute__((address_space(3))) void*)l, 16, 0, 0);
}

// ---------------- weight transpose+convert: in (K,N) f32 -> out (N,K) bf16 ----------------
__global__ __launch_bounds__(256) void transpose_convert(const float* __restrict__ in,
                                                         unsigned short* __restrict__ out,
                                                         int K, int N){
  __shared__ float tile[32][33];
  int n0 = blockIdx.x * 32, k0 = blockIdx.y * 32;
  int t = threadIdx.x; int c = t & 31; int r0 = t >> 5;
  #pragma unroll
  for(int p = 0; p < 4; p++){
    int r = r0 + p * 8;
    tile[r][c] = in[(size_t)(k0 + r) * N + n0 + c];
  }
  __syncthreads();
  #pragma unroll
  for(int p = 0; p < 4; p++){
    int r = r0 + p * 8;
    out[(size_t)(n0 + r) * K + k0 + c] = f2bf(tile[c][r]);
  }
}

// Wq/Wk/Wv fused (all 768x768), z selects the matrix
__global__ __launch_bounds__(256) void transpose_convert_qkv(const float* __restrict__ Wq,
                                                             const float* __restrict__ Wk,
                                                             const float* __restrict__ Wv,
                                                             unsigned short* __restrict__ out){
  __shared__ float tile[32][33];
  const float* in = (blockIdx.z == 0) ? Wq : (blockIdx.z == 1) ? Wk : Wv;
  unsigned short* o = out + (size_t)blockIdx.z * CC * CC;
  int n0 = blockIdx.x * 32, k0 = blockIdx.y * 32;
  int t = threadIdx.x; int c = t & 31; int r0 = t >> 5;
  #pragma unroll
  for(int p = 0; p < 4; p++){
    int r = r0 + p * 8;
    tile[r][c] = in[(size_t)(k0 + r) * CC + n0 + c];
  }
  __syncthreads();
  #pragma unroll
  for(int p = 0; p < 4; p++){
    int r = r0 + p * 8;
    o[(size_t)(n0 + r) * CC + k0 + c] = f2bf(tile[c][r]);
  }
}

__global__ __launch_bounds__(256) void concat_bias(const float* __restrict__ bq,
                                                   const float* __restrict__ bk,
                                                   const float* __restrict__ bv,
                                                   float* __restrict__ bqkv){
  int i = blockIdx.x * 256 + threadIdx.x;
  if(i < 3 * CC) bqkv[i] = (i < CC) ? bq[i] : (i < 2 * CC) ? bk[i - CC] : bv[i - 2 * CC];
}

// ---------------- LayerNorm (fp32 in, fp32+bf16 out), one block per row, C=768 ----------------
__global__ __launch_bounds__(256) void ln_kernel(const float* __restrict__ in,
                                                 const float* __restrict__ gm,
                                                 const float* __restrict__ bt,
                                                 float* __restrict__ out_f,
                                                 unsigned short* __restrict__ out_b){
  int r = blockIdx.x; int t = threadIdx.x;
  const float* row = in + (size_t)r * CC;
  float v0 = row[t], v1 = row[t + 256], v2 = row[t + 512];
  float s = wred_sum(v0 + v1 + v2);
  __shared__ float red[4];
  if((t & 63) == 0) red[t >> 6] = s;
  __syncthreads();
  float mu = (red[0] + red[1] + red[2] + red[3]) * (1.0f / CC);
  float d0 = v0 - mu, d1 = v1 - mu, d2 = v2 - mu;
  float q = wred_sum(d0 * d0 + d1 * d1 + d2 * d2);
  __shared__ float red2[4];
  if((t & 63) == 0) red2[t >> 6] = q;
  __syncthreads();
  float var = (red2[0] + red2[1] + red2[2] + red2[3]) * (1.0f / CC);
  float rinv = rsqrtf(var + 1e-3f);
  float o0 = d0 * rinv * gm[t]       + bt[t];
  float o1 = d1 * rinv * gm[t + 256] + bt[t + 256];
  float o2 = d2 * rinv * gm[t + 512] + bt[t + 512];
  size_t base = (size_t)r * CC;
  if(out_f){ out_f[base + t] = o0; out_f[base + t + 256] = o1; out_f[base + t + 512] = o2; }
  out_b[base + t] = f2bf(o0); out_b[base + t + 256] = f2bf(o1); out_b[base + t + 512] = f2bf(o2);
}

// ---------------- GEMM: C[M,N] = A[M,K](bf16) x Bt[N,K](bf16) + bias ----
// TILE x TILE tile, BK=64, double-buffered 2-phase loop (T3 minimum): issue
// STAGE(t+1) into other buffer, compute t, one vmcnt(0)+raw-barrier per iter.
// Staging: global_load_lds w16, linear dest + inverse-swizzled source (rule 21).
// MODE 0: +bias bf16 (QKV); 1: +bias GELU bf16 (MLP1); 2: +bias +resid f32 (MLP2).
template<int MODE, int TILE>
__global__ __launch_bounds__(256) void gemm_bt(const unsigned short* __restrict__ A,
                                               const unsigned short* __restrict__ Bt,
                                               const float* __restrict__ bias,
                                               const float* __restrict__ resid,
                                               void* __restrict__ outp,
                                               int M, int N, int K){
  constexpr int F = TILE / 32;   // MFMA frags per wave dim (wave-tile = TILE/2)
  constexpr int R = TILE / 32;   // stage rounds per wave per operand
  __shared__ unsigned short As[2][TILE * 64];
  __shared__ unsigned short Bs[2][TILE * 64];
  int m0 = blockIdx.y * TILE, n0 = blockIdx.x * TILE;
  int t = threadIdx.x; int w = t >> 6; int l = t & 63;
  int g = l >> 4; int lc = l & 15;
  int wm = w >> 1, wn = w & 1;
  f32x4 zero4 = {0.f, 0.f, 0.f, 0.f};
  f32x4 acc[F][F];
  #pragma unroll
  for(int mi = 0; mi < F; mi++)
    #pragma unroll
    for(int ni = 0; ni < F; ni++) acc[mi][ni] = zero4;

  auto stage = [&](int ks, int cb){
    #pragma unroll
    for(int p = 0; p < R; p++){
      int e = (w * R + p) * 512 + l * 8;
      int r = e >> 6, clin = e & 63;
      int csrc = clin ^ ((r & 7) << 3);
      gload_lds16(A  + (size_t)(m0 + r) * K + ks + csrc, &As[cb][(w * R + p) * 512]);
      gload_lds16(Bt + (size_t)(n0 + r) * K + ks + csrc, &Bs[cb][(w * R + p) * 512]);
    }
  };

  int nt = K >> 6;
  stage(0, 0);
  asm volatile("s_waitcnt vmcnt(0)" ::: "memory");
  __builtin_amdgcn_s_barrier();
  int cur = 0;
  for(int ti = 0; ti < nt; ti++){
    if(ti + 1 < nt) stage((ti + 1) << 6, cur ^ 1);
    #pragma unroll
    for(int kk = 0; kk < 2; kk++){
      bf16x8 af[F], bfv[F];
      #pragma unroll
      for(int mi = 0; mi < F; mi++) af[mi]  = *(const bf16x8*)&As[cur][swz(wm * (TILE / 2) + mi * 16 + lc, kk * 32 + g * 8)];
      #pragma unroll
      for(int ni = 0; ni < F; ni++) bfv[ni] = *(const bf16x8*)&Bs[cur][swz(wn * (TILE / 2) + ni * 16 + lc, kk * 32 + g * 8)];
      #pragma unroll
      for(int mi = 0; mi < F; mi++)
        #pragma unroll
        for(int ni = 0; ni < F; ni++)
          acc[mi][ni] = __builtin_amdgcn_mfma_f32_16x16x32_bf16(af[mi], bfv[ni], acc[mi][ni], 0, 0, 0);
    }
    asm volatile("s_waitcnt vmcnt(0)" ::: "memory");
    __builtin_amdgcn_s_barrier();
    cur ^= 1;
  }
  #pragma unroll
  for(int mi = 0; mi < F; mi++)
    #pragma unroll
    for(int ni = 0; ni < F; ni++){
      int col = n0 + wn * (TILE / 2) + ni * 16 + lc;
      float bvv = bias[col];
      #pragma unroll
      for(int rr = 0; rr < 4; rr++){
        int row = m0 + wm * (TILE / 2) + mi * 16 + g * 4 + rr;
        float v = acc[mi][ni][rr] + bvv;
        size_t idx = (size_t)row * N + col;
        if(MODE == 1) v = gelu_exact(v);
        if(MODE == 2) ((float*)outp)[idx] = v + resid[idx];
        else          ((unsigned short*)outp)[idx] = f2bf(v);
      }
    }
}

// ---------------- V transpose: qkv v-part (B,T,H,dh) -> vt (B,H,dh,T) ----------------
__global__ __launch_bounds__(256) void transpose_v(const unsigned short* __restrict__ qkv,
                                                   unsigned short* __restrict__ vt){
  __shared__ unsigned short tile[64][65];
  int t0 = blockIdx.x * 64; int bh = blockIdx.y;
  int b = bh / HH, h = bh % HH;
  int t = threadIdx.x;
  #pragma unroll
  for(int p = 0; p < 2; p++){
    int idx = p * 256 + t; int r = idx >> 3; int c = (idx & 7) * 8;
    bf16x8 v = *(const bf16x8*)(qkv + (size_t)(b * TT + t0 + r) * (3 * CC) + 2 * CC + h * DH + c);
    #pragma unroll
    for(int e = 0; e < 8; e++) tile[r][c + e] = (unsigned short)v[e];
  }
  __syncthreads();
  #pragma unroll
  for(int p = 0; p < 2; p++){
    int idx = p * 256 + t; int d = idx >> 3; int c = (idx & 7) * 8;
    bf16x8 v;
    #pragma unroll
    for(int e = 0; e < 8; e++) v[e] = (short)tile[c + e][d];
    *(bf16x8*)(vt + (size_t)(bh * DH + d) * TT + t0 + c) = v;
  }
}

// ---------------- Flash attention v3: 8-wave blocks, LDS-shared q/V staging ----
// Reference semantics: score[i,j] = k_i . q_j, mask j<=i, softmax over j.
// Block handles rows [bx*128, bx*128+128): wave w owns i-tile bx*8+w (16 rows).
// Block mapping: xcd=o&7, q=o>>3 -> head=xcd*3+q%3, bx=15-q/3 (same-head blocks
// share an XCD L2; heaviest blocks dispatch first).
__global__ __launch_bounds__(512) void attn_kernel(const unsigned short* __restrict__ qkv,
                                                   const unsigned short* __restrict__ vt,
                                                   const float* __restrict__ xln,
                                                   float* __restrict__ x1){
  __shared__ unsigned short Aq[2][64 * 64];
  __shared__ unsigned short Vs[2][64 * 64];
  __shared__ unsigned short Ps[8][16 * 64];
  int o = blockIdx.x;
  int xcd = o & 7, qq = o >> 3;          // qq 0..47
  int head = xcd * 3 + (qq % 3);         // 0..23
  int bx = 15 - qq / 3;                  // 15..0 (heavy first)
  int b = head / HH, h = head % HH;
  int t = threadIdx.x; int w = t >> 6; int l = t & 63;
  int g = l >> 4, lc = l & 15;
  int i0w = bx * 128 + w * 16;
  int irow = i0w + lc;
  unsigned short* pw = &Ps[w][0];
  const float SC = 0.125f * 1.44269504f;  // score scale in log2 domain
  const float THR = 11.5f;                // defer-max threshold (~e^8)

  int r_st = t >> 3;
  int c0 = (t & 7) * 8;
  int csrc = c0 ^ ((r_st & 7) << 3);     // inverse-swizzled source column

  bf16x8 bk[2];
  #pragma unroll
  for(int kk = 0; kk < 2; kk++)
    bk[kk] = *(const bf16x8*)(qkv + (size_t)(b * TT + irow) * (3 * CC) + CC + h * DH + kk * 32 + g * 8);

  float m_ = -1e30f, lsum = 0.f;
  f32x4 zero4 = {0.f, 0.f, 0.f, 0.f};
  f32x4 o4[4];
  #pragma unroll
  for(int ds = 0; ds < 4; ds++) o4[ds] = zero4;

  int NJT_w = (i0w + 16 + 63) >> 6;
  int NJTmax = 2 * bx + 2;

  gload_lds16(qkv + (size_t)(b * TT + 0 + r_st) * (3 * CC) + h * DH + csrc, &Aq[0][w * 512]);
  gload_lds16(vt  + (size_t)(head * DH + r_st) * TT + 0 + csrc,             &Vs[0][w * 512]);
  __syncthreads();

  int buf = 0;
  for(int jt = 0; jt < NJTmax; jt++){
    int j0 = jt * 64;
    if(jt + 1 < NJTmax){
      int j1 = j0 + 64;
      gload_lds16(qkv + (size_t)(b * TT + j1 + r_st) * (3 * CC) + h * DH + csrc, &Aq[buf ^ 1][w * 512]);
      gload_lds16(vt  + (size_t)(head * DH + r_st) * TT + j1 + csrc,             &Vs[buf ^ 1][w * 512]);
    }
    if(jt < NJT_w){
      f32x4 s[4];
      #pragma unroll
      for(int js = 0; js < 4; js++){
        s[js] = zero4;
        #pragma unroll
        for(int kk = 0; kk < 2; kk++){
          bf16x8 aq = *(const bf16x8*)&Aq[buf][swz(js * 16 + lc, kk * 32 + g * 8)];
          s[js] = __builtin_amdgcn_mfma_f32_16x16x32_bf16(aq, bk[kk], s[js], 0, 0, 0);
        }
      }
      float mx = -1e30f;
      #pragma unroll
      for(int js = 0; js < 4; js++)
        #pragma unroll
        for(int rr = 0; rr < 4; rr++){
          int j = j0 + js * 16 + g * 4 + rr;
          float sv = s[js][rr] * SC;
          sv = (j <= irow) ? sv : -1e30f;
          s[js][rr] = sv;
          mx = fmaxf(mx, sv);
        }
      mx = fmaxf(mx, __shfl_xor(mx, 16, 64));
      mx = fmaxf(mx, __shfl_xor(mx, 32, 64));
      if(__any(mx > m_ + THR)){
        float mn = fmaxf(m_, mx);
        float al = exp2f(m_ - mn);
        m_ = mn;
        lsum *= al;
        #pragma unroll
        for(int rr = 0; rr < 4; rr++){
          float alb = __shfl(al, g * 4 + rr, 64);
          #pragma unroll
          for(int ds = 0; ds < 4; ds++) o4[ds][rr] *= alb;
        }
      }
      float rsum = 0.f;
      #pragma unroll
      for(int js = 0; js < 4; js++)
        #pragma unroll
        for(int rr = 0; rr < 4; rr++){
          float pv = exp2f(s[js][rr] - m_);
          s[js][rr] = pv;
          rsum += pv;
        }
      rsum += __shfl_xor(rsum, 16, 64);
      rsum += __shfl_xor(rsum, 32, 64);
      lsum += rsum;
      #pragma unroll
      for(int js = 0; js < 4; js++){
        u16x4 pk;
        #pragma unroll
        for(int rr = 0; rr < 4; rr++) pk[rr] = f2bf(s[js][rr]);
        *(u16x4*)&pw[swz(lc, js * 16 + g * 4)] = pk;
      }
      bf16x8 pa[2];
      #pragma unroll
      for(int kk = 0; kk < 2; kk++)
        pa[kk] = *(const bf16x8*)&pw[swz(lc, kk * 32 + g * 8)];
      #pragma unroll
      for(int ds = 0; ds < 4; ds++)
        #pragma unroll
        for(int kk = 0; kk < 2; kk++){
          bf16x8 vb = *(const bf16x8*)&Vs[buf][swz(ds * 16 + lc, kk * 32 + g * 8)];
          o4[ds] = __builtin_amdgcn_mfma_f32_16x16x32_bf16(pa[kk], vb, o4[ds], 0, 0, 0);
        }
    }
    __syncthreads();
    buf ^= 1;
  }
  #pragma unroll
  for(int rr = 0; rr < 4; rr++){
    float lsb = __shfl(lsum, g * 4 + rr, 64);
    float rinv = 1.0f / lsb;
    int ig = i0w + g * 4 + rr;
    #pragma unroll
    for(int ds = 0; ds < 4; ds++){
      int col = h * DH + ds * 16 + lc;
      size_t idx = (size_t)(b * TT + ig) * CC + col;
      x1[idx] = xln[idx] + o4[ds][rr] * rinv;
    }
  }
}

// ---------------- host launcher ----------------
extern "C" void kernel_launch(void* const* d_in, const int* in_sizes, int n_in,
                              void* d_out, int out_size, void* d_ws, size_t ws_size,
                              hipStream_t stream){
  const float* x    = (const float*)d_in[0];
  const float* ln1g = (const float*)d_in[1];
  const float* ln1b = (const float*)d_in[2];
  const float* Wq   = (const float*)d_in[3];
  const float* bq   = (const float*)d_in[4];
  const float* Wk   = (const float*)d_in[5];
  const float* bk   = (const float*)d_in[6];
  const float* Wv   = (const float*)d_in[7];
  const float* bv   = (const float*)d_in[8];
  const float* ln2g = (const float*)d_in[9];
  const float* ln2b = (const float*)d_in[10];
  const float* W1   = (const float*)d_in[11];
  const float* b1   = (const float*)d_in[12];
  const float* W2   = (const float*)d_in[13];
  const float* b2   = (const float*)d_in[14];

  char* ws = (char*)d_ws;
  float*          xlnf = (float*)(ws + 0);                  // 12582912 B
  unsigned short* xlnb = (unsigned short*)(ws + 12582912);  // 6291456
  float*          x1   = (float*)(ws + 18874368);           // 12582912
  unsigned short* hln2 = (unsigned short*)(ws + 31457280);  // 6291456
  unsigned short* wqkv = (unsigned short*)(ws + 37748736);  // 3538944
  float*          bqkv = (float*)(ws + 41287680);           // 9216
  unsigned short* w1t  = (unsigned short*)(ws + 41296896);  // 4718592
  unsigned short* w2t  = (unsigned short*)(ws + 46015488);  // 4718592
  unsigned short* qkv  = (unsigned short*)(ws + 50734080);  // 18874368
  unsigned short* vt   = (unsigned short*)(ws + 69608448);  // 6291456
  unsigned short* mlp1 = (unsigned short*)(ws + 50734080);  // aliases qkv+vt (dead by then)

  transpose_convert_qkv<<<dim3(24, 24, 3), 256, 0, stream>>>(Wq, Wk, Wv, wqkv);
  transpose_convert<<<dim3(96, 24), 256, 0, stream>>>(W1, w1t, CC, 4 * CC);
  transpose_convert<<<dim3(24, 96), 256, 0, stream>>>(W2, w2t, 4 * CC, CC);
  concat_bias<<<9, 256, 0, stream>>>(bq, bk, bv, bqkv);

  ln_kernel<<<NROWS, 256, 0, stream>>>(x, ln1g, ln1b, xlnf, xlnb);

  gemm_bt<0, 128><<<dim3(18, 32), 256, 0, stream>>>(xlnb, wqkv, bqkv, nullptr, qkv, NROWS, 3 * CC, CC);

  transpose_v<<<dim3(TT / 64, BB * HH), 256, 0, stream>>>(qkv, vt);

  attn_kernel<<<dim3(384), 512, 0, stream>>>(qkv, vt, xlnf, x1);

  ln_kernel<<<NROWS, 256, 0, stream>>>(x1, ln2g, ln2b, nullptr, hln2);

  gemm_bt<1, 128><<<dim3(24, 32), 256, 0, stream>>>(hln2, w1t, b1, nullptr, mlp1, NROWS, 4 * CC, CC);

  gemm_bt<2, 64><<<dim3(12, 64), 256, 0, stream>>>(mlp1, w2t, b2, x1, d_out, NROWS, CC, 4 * CC);

  (void)in_sizes; (void)n_in; (void)out_size; (void)ws_size;
}

// Round 5
// 192.593 us; speedup vs baseline: 1.6629x; 1.0433x over previous
//
#include <hip/hip_runtime.h>
#include <hip/hip_bf16.h>
#include <cmath>

// Decoder block: LN1 -> QKV -> (swapped) causal attention -> residual -> LN2 -> MLP(GELU) -> residual
// B=2, T=2048, C=768, H=12, dh=64. All GEMMs bf16 MFMA 16x16x32, fp32 accumulate.

#define BB 2
#define TT 2048
#define CC 768
#define HH 12
#define DH 64
#define NROWS (BB*TT)   // 4096

typedef __attribute__((ext_vector_type(8))) short bf16x8;
typedef __attribute__((ext_vector_type(4))) float f32x4;
typedef __attribute__((ext_vector_type(4))) unsigned short u16x4;

__device__ __forceinline__ unsigned short f2bf(float f){
  union { __hip_bfloat16 h; unsigned short u; } c;
  c.h = __float2bfloat16(f);
  return c.u;
}
// XOR-swizzle for [rows][64] bf16 LDS tiles (128B rows). Returns ELEMENT index.
__device__ __forceinline__ int swz(int r, int c){
  int b = (r << 7) + (c << 1);
  b ^= (r & 7) << 4;
  return b >> 1;
}
__device__ __forceinline__ float wred_sum(float v){
  #pragma unroll
  for(int m = 1; m < 64; m <<= 1) v += __shfl_xor(v, m, 64);
  return v;
}
__device__ __forceinline__ float gelu_exact(float x){
  return 0.5f * x * (1.0f + erff(x * 0.70710678118654752f));
}
// async global->LDS, 16B per lane; dest = wave-uniform base + lane*16
__device__ __forceinline__ void gload_lds16(const void* g, void* l){
  __builtin_amdgcn_global_load_lds((const __attribute__((address_space(1))) void*)g,
                                   (__attribute__((address_space(3))) void*)l, 16, 0, 0);
}

// ---------------- weight transpose+convert: in (K,N) f32 -> out (N,K) bf16 ----------------
__global__ __launch_bounds__(256) void transpose_convert(const float* __restrict__ in,
                                                         unsigned short* __restrict__ out,
                                                         int K, int N){
  __shared__ float tile[32][33];
  int n0 = blockIdx.x * 32, k0 = blockIdx.y * 32;
  int t = threadIdx.x; int c = t & 31; int r0 = t >> 5;
  #pragma unroll
  for(int p = 0; p < 4; p++){
    int r = r0 + p * 8;
    tile[r][c] = in[(size_t)(k0 + r) * N + n0 + c];
  }
  __syncthreads();
  #pragma unroll
  for(int p = 0; p < 4; p++){
    int r = r0 + p * 8;
    out[(size_t)(n0 + r) * K + k0 + c] = f2bf(tile[c][r]);
  }
}

// Wq/Wk/Wv fused (all 768x768), z selects the matrix
__global__ __launch_bounds__(256) void transpose_convert_qkv(const float* __restrict__ Wq,
                                                             const float* __restrict__ Wk,
                                                             const float* __restrict__ Wv,
                                                             unsigned short* __restrict__ out){
  __shared__ float tile[32][33];
  const float* in = (blockIdx.z == 0) ? Wq : (blockIdx.z == 1) ? Wk : Wv;
  unsigned short* o = out + (size_t)blockIdx.z * CC * CC;
  int n0 = blockIdx.x * 32, k0 = blockIdx.y * 32;
  int t = threadIdx.x; int c = t & 31; int r0 = t >> 5;
  #pragma unroll
  for(int p = 0; p < 4; p++){
    int r = r0 + p * 8;
    tile[r][c] = in[(size_t)(k0 + r) * CC + n0 + c];
  }
  __syncthreads();
  #pragma unroll
  for(int p = 0; p < 4; p++){
    int r = r0 + p * 8;
    o[(size_t)(n0 + r) * CC + k0 + c] = f2bf(tile[c][r]);
  }
}

__global__ __launch_bounds__(256) void concat_bias(const float* __restrict__ bq,
                                                   const float* __restrict__ bk,
                                                   const float* __restrict__ bv,
                                                   float* __restrict__ bqkv){
  int i = blockIdx.x * 256 + threadIdx.x;
  if(i < 3 * CC) bqkv[i] = (i < CC) ? bq[i] : (i < 2 * CC) ? bk[i - CC] : bv[i - 2 * CC];
}

// ---------------- LayerNorm (fp32 in, fp32+bf16 out), one block per row, C=768 ----------------
__global__ __launch_bounds__(256) void ln_kernel(const float* __restrict__ in,
                                                 const float* __restrict__ gm,
                                                 const float* __restrict__ bt,
                                                 float* __restrict__ out_f,
                                                 unsigned short* __restrict__ out_b){
  int r = blockIdx.x; int t = threadIdx.x;
  const float* row = in + (size_t)r * CC;
  float v0 = row[t], v1 = row[t + 256], v2 = row[t + 512];
  float s = wred_sum(v0 + v1 + v2);
  __shared__ float red[4];
  if((t & 63) == 0) red[t >> 6] = s;
  __syncthreads();
  float mu = (red[0] + red[1] + red[2] + red[3]) * (1.0f / CC);
  float d0 = v0 - mu, d1 = v1 - mu, d2 = v2 - mu;
  float q = wred_sum(d0 * d0 + d1 * d1 + d2 * d2);
  __shared__ float red2[4];
  if((t & 63) == 0) red2[t >> 6] = q;
  __syncthreads();
  float var = (red2[0] + red2[1] + red2[2] + red2[3]) * (1.0f / CC);
  float rinv = rsqrtf(var + 1e-3f);
  float o0 = d0 * rinv * gm[t]       + bt[t];
  float o1 = d1 * rinv * gm[t + 256] + bt[t + 256];
  float o2 = d2 * rinv * gm[t + 512] + bt[t + 512];
  size_t base = (size_t)r * CC;
  if(out_f){ out_f[base + t] = o0; out_f[base + t + 256] = o1; out_f[base + t + 512] = o2; }
  out_b[base + t] = f2bf(o0); out_b[base + t + 256] = f2bf(o1); out_b[base + t + 512] = f2bf(o2);
}

// ---------------- GEMM: C[M,N] = A[M,K](bf16) x Bt[N,K](bf16) + bias ----
// TILE x TILE tile, BK=64, double-buffered 2-phase loop (T3 minimum).
// MODE 0: +bias bf16 (QKV); 1: +bias GELU bf16 (MLP1); 2: +bias +resid f32 (MLP2).
template<int MODE, int TILE>
__global__ __launch_bounds__(256) void gemm_bt(const unsigned short* __restrict__ A,
                                               const unsigned short* __restrict__ Bt,
                                               const float* __restrict__ bias,
                                               const float* __restrict__ resid,
                                               void* __restrict__ outp,
                                               int M, int N, int K){
  constexpr int F = TILE / 32;
  constexpr int R = TILE / 32;
  __shared__ unsigned short As[2][TILE * 64];
  __shared__ unsigned short Bs[2][TILE * 64];
  int m0 = blockIdx.y * TILE, n0 = blockIdx.x * TILE;
  int t = threadIdx.x; int w = t >> 6; int l = t & 63;
  int g = l >> 4; int lc = l & 15;
  int wm = w >> 1, wn = w & 1;
  f32x4 zero4 = {0.f, 0.f, 0.f, 0.f};
  f32x4 acc[F][F];
  #pragma unroll
  for(int mi = 0; mi < F; mi++)
    #pragma unroll
    for(int ni = 0; ni < F; ni++) acc[mi][ni] = zero4;

  auto stage = [&](int ks, int cb){
    #pragma unroll
    for(int p = 0; p < R; p++){
      int e = (w * R + p) * 512 + l * 8;
      int r = e >> 6, clin = e & 63;
      int csrc = clin ^ ((r & 7) << 3);
      gload_lds16(A  + (size_t)(m0 + r) * K + ks + csrc, &As[cb][(w * R + p) * 512]);
      gload_lds16(Bt + (size_t)(n0 + r) * K + ks + csrc, &Bs[cb][(w * R + p) * 512]);
    }
  };

  int nt = K >> 6;
  stage(0, 0);
  asm volatile("s_waitcnt vmcnt(0)" ::: "memory");
  __builtin_amdgcn_s_barrier();
  int cur = 0;
  for(int ti = 0; ti < nt; ti++){
    if(ti + 1 < nt) stage((ti + 1) << 6, cur ^ 1);
    #pragma unroll
    for(int kk = 0; kk < 2; kk++){
      bf16x8 af[F], bfv[F];
      #pragma unroll
      for(int mi = 0; mi < F; mi++) af[mi]  = *(const bf16x8*)&As[cur][swz(wm * (TILE / 2) + mi * 16 + lc, kk * 32 + g * 8)];
      #pragma unroll
      for(int ni = 0; ni < F; ni++) bfv[ni] = *(const bf16x8*)&Bs[cur][swz(wn * (TILE / 2) + ni * 16 + lc, kk * 32 + g * 8)];
      #pragma unroll
      for(int mi = 0; mi < F; mi++)
        #pragma unroll
        for(int ni = 0; ni < F; ni++)
          acc[mi][ni] = __builtin_amdgcn_mfma_f32_16x16x32_bf16(af[mi], bfv[ni], acc[mi][ni], 0, 0, 0);
    }
    asm volatile("s_waitcnt vmcnt(0)" ::: "memory");
    __builtin_amdgcn_s_barrier();
    cur ^= 1;
  }
  #pragma unroll
  for(int mi = 0; mi < F; mi++)
    #pragma unroll
    for(int ni = 0; ni < F; ni++){
      int col = n0 + wn * (TILE / 2) + ni * 16 + lc;
      float bvv = bias[col];
      #pragma unroll
      for(int rr = 0; rr < 4; rr++){
        int row = m0 + wm * (TILE / 2) + mi * 16 + g * 4 + rr;
        float v = acc[mi][ni][rr] + bvv;
        size_t idx = (size_t)row * N + col;
        if(MODE == 1) v = gelu_exact(v);
        if(MODE == 2) ((float*)outp)[idx] = v + resid[idx];
        else          ((unsigned short*)outp)[idx] = f2bf(v);
      }
    }
}

// ---------------- V transpose: qkv v-part (B,T,H,dh) -> vt (B,H,dh,T) ----------------
__global__ __launch_bounds__(256) void transpose_v(const unsigned short* __restrict__ qkv,
                                                   unsigned short* __restrict__ vt){
  __shared__ unsigned short tile[64][65];
  int t0 = blockIdx.x * 64; int bh = blockIdx.y;
  int b = bh / HH, h = bh % HH;
  int t = threadIdx.x;
  #pragma unroll
  for(int p = 0; p < 2; p++){
    int idx = p * 256 + t; int r = idx >> 3; int c = (idx & 7) * 8;
    bf16x8 v = *(const bf16x8*)(qkv + (size_t)(b * TT + t0 + r) * (3 * CC) + 2 * CC + h * DH + c);
    #pragma unroll
    for(int e = 0; e < 8; e++) tile[r][c + e] = (unsigned short)v[e];
  }
  __syncthreads();
  #pragma unroll
  for(int p = 0; p < 2; p++){
    int idx = p * 256 + t; int d = idx >> 3; int c = (idx & 7) * 8;
    bf16x8 v;
    #pragma unroll
    for(int e = 0; e < 8; e++) v[e] = (short)tile[c + e][d];
    *(bf16x8*)(vt + (size_t)(bh * DH + d) * TT + t0 + c) = v;
  }
}

// ---------------- Flash attention v4: 4-wave / 64-row blocks, lean softmax ----
// Reference semantics: score[i,j] = k_i . q_j, mask j<=i, softmax over j.
// Swapped MFMA: S^T[j][i] at lane (g,lc): i=lc, j=js*16+g*4+rr.
// Scale folded into exp2 arg (FMA); running max in raw-score domain; full tiles
// (j0+63 <= i0w) skip causal masking. Block mapping: xcd=o&7, qq=o>>3 ->
// head=xcd*3+qq%3, bx=31-qq/3 (same-head blocks on one XCD; heavy first).
__global__ __launch_bounds__(256) void attn_kernel(const unsigned short* __restrict__ qkv,
                                                   const unsigned short* __restrict__ vt,
                                                   const float* __restrict__ xln,
                                                   float* __restrict__ x1){
  __shared__ unsigned short Aq[2][64 * 64];
  __shared__ unsigned short Vs[2][64 * 64];
  __shared__ unsigned short Ps[4][16 * 64];
  int o = blockIdx.x;
  int xcd = o & 7, qq = o >> 3;          // qq 0..95
  int head = xcd * 3 + (qq % 3);         // 0..23
  int bx = 31 - qq / 3;                  // 31..0 (heavy first)
  int b = head / HH, h = head % HH;
  int t = threadIdx.x; int w = t >> 6; int l = t & 63;
  int g = l >> 4, lc = l & 15;
  int i0w = bx * 64 + w * 16;
  int irow = i0w + lc;
  unsigned short* pw = &Ps[w][0];
  const float SC = 0.125f * 1.44269504f;   // score scale into log2 domain
  const float RAW_THR = 11.5f / SC;        // defer-max threshold in raw domain

  // staging geometry: wave w, round p -> segment sgi=w*2+p (8 rows); lane l
  // covers row sgi*8 + (l>>3), linear cols (l&7)*8..+7; source col inverse-swizzled.
  int rl = l >> 3;
  int csrc = ((l & 7) * 8) ^ (rl * 8);

  bf16x8 bk[2];
  #pragma unroll
  for(int kk = 0; kk < 2; kk++)
    bk[kk] = *(const bf16x8*)(qkv + (size_t)(b * TT + irow) * (3 * CC) + CC + h * DH + kk * 32 + g * 8);

  float m_ = -1e30f, lsum = 0.f;
  f32x4 zero4 = {0.f, 0.f, 0.f, 0.f};
  f32x4 o4[4];
  #pragma unroll
  for(int ds = 0; ds < 4; ds++) o4[ds] = zero4;

  int NJT_w = (i0w + 16 + 63) >> 6;      // this wave's causal j-tile count
  int NJTmax = bx + 1;                   // block-wide j-tile count

  auto stage = [&](int j0, int cb){
    #pragma unroll
    for(int p = 0; p < 2; p++){
      int sgi = w * 2 + p;
      int row = sgi * 8 + rl;
      gload_lds16(qkv + (size_t)(b * TT + j0 + row) * (3 * CC) + h * DH + csrc, &Aq[cb][sgi * 512]);
      gload_lds16(vt  + (size_t)(head * DH + row) * TT + j0 + csrc,             &Vs[cb][sgi * 512]);
    }
  };

  stage(0, 0);
  __syncthreads();

  int buf = 0;
  for(int jt = 0; jt < NJTmax; jt++){
    int j0 = jt * 64;
    if(jt + 1 < NJTmax) stage(j0 + 64, buf ^ 1);
    if(jt < NJT_w){
      // QK^T (swapped): S^T[j][i]; A = q rows j (LDS), B = k rows i (reg)
      f32x4 s[4];
      __builtin_amdgcn_s_setprio(1);
      #pragma unroll
      for(int js = 0; js < 4; js++){
        s[js] = zero4;
        #pragma unroll
        for(int kk = 0; kk < 2; kk++){
          bf16x8 aq = *(const bf16x8*)&Aq[buf][swz(js * 16 + lc, kk * 32 + g * 8)];
          s[js] = __builtin_amdgcn_mfma_f32_16x16x32_bf16(aq, bk[kk], s[js], 0, 0, 0);
        }
      }
      __builtin_amdgcn_s_setprio(0);
      // tile max in RAW domain; mask only on diagonal tiles
      float mx = -1e30f;
      if(j0 + 63 > i0w){   // diagonal tile: apply causal mask
        #pragma unroll
        for(int js = 0; js < 4; js++)
          #pragma unroll
          for(int rr = 0; rr < 4; rr++){
            int j = j0 + js * 16 + g * 4 + rr;
            float sv = s[js][rr];
            sv = (j <= irow) ? sv : -1e30f;
            s[js][rr] = sv;
            mx = fmaxf(mx, sv);
          }
      } else {
        #pragma unroll
        for(int js = 0; js < 4; js++)
          #pragma unroll
          for(int rr = 0; rr < 4; rr++) mx = fmaxf(mx, s[js][rr]);
      }
      mx = fmaxf(mx, __shfl_xor(mx, 16, 64));
      mx = fmaxf(mx, __shfl_xor(mx, 32, 64));
      if(__any(mx > m_ + RAW_THR)){
        float mn = fmaxf(m_, mx);
        float al = exp2f((m_ - mn) * SC);
        m_ = mn;
        lsum *= al;
        #pragma unroll
        for(int rr = 0; rr < 4; rr++){
          float alb = __shfl(al, g * 4 + rr, 64);
          #pragma unroll
          for(int ds = 0; ds < 4; ds++) o4[ds][rr] *= alb;
        }
      }
      float nmSC = -m_ * SC;
      float rsum = 0.f;
      #pragma unroll
      for(int js = 0; js < 4; js++)
        #pragma unroll
        for(int rr = 0; rr < 4; rr++){
          float pv = exp2f(fmaf(s[js][rr], SC, nmSC));
          s[js][rr] = pv;
          rsum += pv;
        }
      rsum += __shfl_xor(rsum, 16, 64);
      rsum += __shfl_xor(rsum, 32, 64);
      lsum += rsum;
      // P -> wave-private LDS (pw[i=lc][j], swizzled)
      #pragma unroll
      for(int js = 0; js < 4; js++){
        u16x4 pk;
        #pragma unroll
        for(int rr = 0; rr < 4; rr++) pk[rr] = f2bf(s[js][rr]);
        *(u16x4*)&pw[swz(lc, js * 16 + g * 4)] = pk;
      }
      bf16x8 pa[2];
      #pragma unroll
      for(int kk = 0; kk < 2; kk++)
        pa[kk] = *(const bf16x8*)&pw[swz(lc, kk * 32 + g * 8)];
      __builtin_amdgcn_s_setprio(1);
      #pragma unroll
      for(int ds = 0; ds < 4; ds++)
        #pragma unroll
        for(int kk = 0; kk < 2; kk++){
          bf16x8 vb = *(const bf16x8*)&Vs[buf][swz(ds * 16 + lc, kk * 32 + g * 8)];
          o4[ds] = __builtin_amdgcn_mfma_f32_16x16x32_bf16(pa[kk], vb, o4[ds], 0, 0, 0);
        }
      __builtin_amdgcn_s_setprio(0);
    }
    __syncthreads();
    buf ^= 1;
  }
  // epilogue: o rows i = g*4+rr, cols d = ds*16+lc; softmax state lives at lane lc=i
  #pragma unroll
  for(int rr = 0; rr < 4; rr++){
    float lsb = __shfl(lsum, g * 4 + rr, 64);
    float rinv = 1.0f / lsb;
    int ig = i0w + g * 4 + rr;
    #pragma unroll
    for(int ds = 0; ds < 4; ds++){
      int col = h * DH + ds * 16 + lc;
      size_t idx = (size_t)(b * TT + ig) * CC + col;
      x1[idx] = xln[idx] + o4[ds][rr] * rinv;
    }
  }
}

// ---------------- host launcher ----------------
extern "C" void kernel_launch(void* const* d_in, const int* in_sizes, int n_in,
                              void* d_out, int out_size, void* d_ws, size_t ws_size,
                              hipStream_t stream){
  const float* x    = (const float*)d_in[0];
  const float* ln1g = (const float*)d_in[1];
  const float* ln1b = (const float*)d_in[2];
  const float* Wq   = (const float*)d_in[3];
  const float* bq   = (const float*)d_in[4];
  const float* Wk   = (const float*)d_in[5];
  const float* bk   = (const float*)d_in[6];
  const float* Wv   = (const float*)d_in[7];
  const float* bv   = (const float*)d_in[8];
  const float* ln2g = (const float*)d_in[9];
  const float* ln2b = (const float*)d_in[10];
  const float* W1   = (const float*)d_in[11];
  const float* b1   = (const float*)d_in[12];
  const float* W2   = (const float*)d_in[13];
  const float* b2   = (const float*)d_in[14];

  char* ws = (char*)d_ws;
  float*          xlnf = (float*)(ws + 0);                  // 12582912 B
  unsigned short* xlnb = (unsigned short*)(ws + 12582912);  // 6291456
  float*          x1   = (float*)(ws + 18874368);           // 12582912
  unsigned short* hln2 = (unsigned short*)(ws + 31457280);  // 6291456
  unsigned short* wqkv = (unsigned short*)(ws + 37748736);  // 3538944
  float*          bqkv = (float*)(ws + 41287680);           // 9216
  unsigned short* w1t  = (unsigned short*)(ws + 41296896);  // 4718592
  unsigned short* w2t  = (unsigned short*)(ws + 46015488);  // 4718592
  unsigned short* qkv  = (unsigned short*)(ws + 50734080);  // 18874368
  unsigned short* vt   = (unsigned short*)(ws + 69608448);  // 6291456
  unsigned short* mlp1 = (unsigned short*)(ws + 50734080);  // aliases qkv+vt (dead by then)

  transpose_convert_qkv<<<dim3(24, 24, 3), 256, 0, stream>>>(Wq, Wk, Wv, wqkv);
  transpose_convert<<<dim3(96, 24), 256, 0, stream>>>(W1, w1t, CC, 4 * CC);
  transpose_convert<<<dim3(24, 96), 256, 0, stream>>>(W2, w2t, 4 * CC, CC);
  concat_bias<<<9, 256, 0, stream>>>(bq, bk, bv, bqkv);

  ln_kernel<<<NROWS, 256, 0, stream>>>(x, ln1g, ln1b, xlnf, xlnb);

  gemm_bt<0, 128><<<dim3(18, 32), 256, 0, stream>>>(xlnb, wqkv, bqkv, nullptr, qkv, NROWS, 3 * CC, CC);

  transpose_v<<<dim3(TT / 64, BB * HH), 256, 0, stream>>>(qkv, vt);

  attn_kernel<<<dim3(768), 256, 0, stream>>>(qkv, vt, xlnf, x1);

  ln_kernel<<<NROWS, 256, 0, stream>>>(x1, ln2g, ln2b, nullptr, hln2);

  gemm_bt<1, 128><<<dim3(24, 32), 256, 0, stream>>>(hln2, w1t, b1, nullptr, mlp1, NROWS, 4 * CC, CC);

  gemm_bt<2, 64><<<dim3(12, 64), 256, 0, stream>>>(mlp1, w2t, b2, x1, d_out, NROWS, CC, 4 * CC);

  (void)in_sizes; (void)n_in; (void)out_size; (void)ws_size;
}

// Round 6
// 183.336 us; speedup vs baseline: 1.7468x; 1.0505x over previous
//
#include <hip/hip_runtime.h>
#include <hip/hip_bf16.h>
#include <cmath>

// Decoder block: LN1 -> QKV -> (swapped) causal attention -> residual -> LN2 -> MLP(GELU) -> residual
// B=2, T=2048, C=768, H=12, dh=64. All GEMMs bf16 MFMA 16x16x32, fp32 accumulate.

#define BB 2
#define TT 2048
#define CC 768
#define HH 12
#define DH 64
#define NROWS (BB*TT)   // 4096

typedef __attribute__((ext_vector_type(8))) short bf16x8;
typedef __attribute__((ext_vector_type(4))) float f32x4;
typedef __attribute__((ext_vector_type(4))) unsigned short u16x4;

__device__ __forceinline__ unsigned short f2bf(float f){
  union { __hip_bfloat16 h; unsigned short u; } c;
  c.h = __float2bfloat16(f);
  return c.u;
}
// XOR-swizzle for [rows][64] bf16 LDS tiles (128B rows). Returns ELEMENT index.
__device__ __forceinline__ int swz(int r, int c){
  int b = (r << 7) + (c << 1);
  b ^= (r & 7) << 4;
  return b >> 1;
}
__device__ __forceinline__ float wred_sum(float v){
  #pragma unroll
  for(int m = 1; m < 64; m <<= 1) v += __shfl_xor(v, m, 64);
  return v;
}
__device__ __forceinline__ float gelu_exact(float x){
  return 0.5f * x * (1.0f + erff(x * 0.70710678118654752f));
}
// async global->LDS, 16B per lane; dest = wave-uniform base + lane*16
__device__ __forceinline__ void gload_lds16(const void* g, void* l){
  __builtin_amdgcn_global_load_lds((const __attribute__((address_space(1))) void*)g,
                                   (__attribute__((address_space(3))) void*)l, 16, 0, 0);
}
// counted vmcnt wait (immediate must be a literal)
template<int N> __device__ __forceinline__ void waitcnt_vm(){
  if constexpr (N == 0)      asm volatile("s_waitcnt vmcnt(0)" ::: "memory");
  else if constexpr (N == 4) asm volatile("s_waitcnt vmcnt(4)" ::: "memory");
  else if constexpr (N == 8) asm volatile("s_waitcnt vmcnt(8)" ::: "memory");
  else static_assert(N == 0 || N == 4 || N == 8, "unsupported vmcnt");
}

// ---------------- weight transpose+convert: in (K,N) f32 -> out (N,K) bf16 ----------------
__global__ __launch_bounds__(256) void transpose_convert(const float* __restrict__ in,
                                                         unsigned short* __restrict__ out,
                                                         int K, int N){
  __shared__ float tile[32][33];
  int n0 = blockIdx.x * 32, k0 = blockIdx.y * 32;
  int t = threadIdx.x; int c = t & 31; int r0 = t >> 5;
  #pragma unroll
  for(int p = 0; p < 4; p++){
    int r = r0 + p * 8;
    tile[r][c] = in[(size_t)(k0 + r) * N + n0 + c];
  }
  __syncthreads();
  #pragma unroll
  for(int p = 0; p < 4; p++){
    int r = r0 + p * 8;
    out[(size_t)(n0 + r) * K + k0 + c] = f2bf(tile[c][r]);
  }
}

// Wq/Wk/Wv fused (all 768x768), z selects the matrix
__global__ __launch_bounds__(256) void transpose_convert_qkv(const float* __restrict__ Wq,
                                                             const float* __restrict__ Wk,
                                                             const float* __restrict__ Wv,
                                                             unsigned short* __restrict__ out){
  __shared__ float tile[32][33];
  const float* in = (blockIdx.z == 0) ? Wq : (blockIdx.z == 1) ? Wk : Wv;
  unsigned short* o = out + (size_t)blockIdx.z * CC * CC;
  int n0 = blockIdx.x * 32, k0 = blockIdx.y * 32;
  int t = threadIdx.x; int c = t & 31; int r0 = t >> 5;
  #pragma unroll
  for(int p = 0; p < 4; p++){
    int r = r0 + p * 8;
    tile[r][c] = in[(size_t)(k0 + r) * CC + n0 + c];
  }
  __syncthreads();
  #pragma unroll
  for(int p = 0; p < 4; p++){
    int r = r0 + p * 8;
    o[(size_t)(n0 + r) * CC + k0 + c] = f2bf(tile[c][r]);
  }
}

__global__ __launch_bounds__(256) void concat_bias(const float* __restrict__ bq,
                                                   const float* __restrict__ bk,
                                                   const float* __restrict__ bv,
                                                   float* __restrict__ bqkv){
  int i = blockIdx.x * 256 + threadIdx.x;
  if(i < 3 * CC) bqkv[i] = (i < CC) ? bq[i] : (i < 2 * CC) ? bk[i - CC] : bv[i - 2 * CC];
}

// ---------------- LayerNorm (fp32 in, fp32+bf16 out), one block per row, C=768 ----------------
__global__ __launch_bounds__(256) void ln_kernel(const float* __restrict__ in,
                                                 const float* __restrict__ gm,
                                                 const float* __restrict__ bt,
                                                 float* __restrict__ out_f,
                                                 unsigned short* __restrict__ out_b){
  int r = blockIdx.x; int t = threadIdx.x;
  const float* row = in + (size_t)r * CC;
  float v0 = row[t], v1 = row[t + 256], v2 = row[t + 512];
  float s = wred_sum(v0 + v1 + v2);
  __shared__ float red[4];
  if((t & 63) == 0) red[t >> 6] = s;
  __syncthreads();
  float mu = (red[0] + red[1] + red[2] + red[3]) * (1.0f / CC);
  float d0 = v0 - mu, d1 = v1 - mu, d2 = v2 - mu;
  float q = wred_sum(d0 * d0 + d1 * d1 + d2 * d2);
  __shared__ float red2[4];
  if((t & 63) == 0) red2[t >> 6] = q;
  __syncthreads();
  float var = (red2[0] + red2[1] + red2[2] + red2[3]) * (1.0f / CC);
  float rinv = rsqrtf(var + 1e-3f);
  float o0 = d0 * rinv * gm[t]       + bt[t];
  float o1 = d1 * rinv * gm[t + 256] + bt[t + 256];
  float o2 = d2 * rinv * gm[t + 512] + bt[t + 512];
  size_t base = (size_t)r * CC;
  if(out_f){ out_f[base + t] = o0; out_f[base + t + 256] = o1; out_f[base + t + 512] = o2; }
  out_b[base + t] = f2bf(o0); out_b[base + t + 256] = f2bf(o1); out_b[base + t + 512] = f2bf(o2);
}

// ---------------- GEMM: C[M,N] = A[M,K](bf16) x Bt[N,K](bf16) + bias ----
// TILE x TILE tile, BK=64, depth-2 counted-vmcnt pipeline (T3+T4):
//   prologue: stage(0), stage(1)
//   iter t:   vmcnt(NLD) [stage(t) done, stage(t+1) in flight] -> barrier ->
//             compute(t) -> barrier -> stage(t+2)
// MODE 0: +bias bf16 (QKV); 1: +bias GELU bf16 (MLP1); 2: +bias +resid f32 (MLP2).
template<int MODE, int TILE>
__global__ __launch_bounds__(256) void gemm_bt(const unsigned short* __restrict__ A,
                                               const unsigned short* __restrict__ Bt,
                                               const float* __restrict__ bias,
                                               const float* __restrict__ resid,
                                               void* __restrict__ outp,
                                               int M, int N, int K){
  constexpr int F = TILE / 32;
  constexpr int R = TILE / 32;       // stage rounds per wave per operand
  constexpr int NLD = 2 * R;         // vmem instrs per wave per stage()
  __shared__ unsigned short As[2][TILE * 64];
  __shared__ unsigned short Bs[2][TILE * 64];
  int m0 = blockIdx.y * TILE, n0 = blockIdx.x * TILE;
  int t = threadIdx.x; int w = t >> 6; int l = t & 63;
  int g = l >> 4; int lc = l & 15;
  int wm = w >> 1, wn = w & 1;
  f32x4 zero4 = {0.f, 0.f, 0.f, 0.f};
  f32x4 acc[F][F];
  #pragma unroll
  for(int mi = 0; mi < F; mi++)
    #pragma unroll
    for(int ni = 0; ni < F; ni++) acc[mi][ni] = zero4;

  auto stage = [&](int ks, int cb){
    #pragma unroll
    for(int p = 0; p < R; p++){
      int e = (w * R + p) * 512 + l * 8;
      int r = e >> 6, clin = e & 63;
      int csrc = clin ^ ((r & 7) << 3);
      gload_lds16(A  + (size_t)(m0 + r) * K + ks + csrc, &As[cb][(w * R + p) * 512]);
      gload_lds16(Bt + (size_t)(n0 + r) * K + ks + csrc, &Bs[cb][(w * R + p) * 512]);
    }
  };

  int nt = K >> 6;
  stage(0, 0);
  if(nt > 1) stage(64, 1);
  for(int ti = 0; ti < nt; ti++){
    if(ti + 1 < nt) waitcnt_vm<NLD>(); else waitcnt_vm<0>();
    __builtin_amdgcn_s_barrier();
    int cur = ti & 1;
    #pragma unroll
    for(int kk = 0; kk < 2; kk++){
      bf16x8 af[F], bfv[F];
      #pragma unroll
      for(int mi = 0; mi < F; mi++) af[mi]  = *(const bf16x8*)&As[cur][swz(wm * (TILE / 2) + mi * 16 + lc, kk * 32 + g * 8)];
      #pragma unroll
      for(int ni = 0; ni < F; ni++) bfv[ni] = *(const bf16x8*)&Bs[cur][swz(wn * (TILE / 2) + ni * 16 + lc, kk * 32 + g * 8)];
      #pragma unroll
      for(int mi = 0; mi < F; mi++)
        #pragma unroll
        for(int ni = 0; ni < F; ni++)
          acc[mi][ni] = __builtin_amdgcn_mfma_f32_16x16x32_bf16(af[mi], bfv[ni], acc[mi][ni], 0, 0, 0);
    }
    __builtin_amdgcn_s_barrier();
    if(ti + 2 < nt) stage((ti + 2) << 6, cur);
  }
  #pragma unroll
  for(int mi = 0; mi < F; mi++)
    #pragma unroll
    for(int ni = 0; ni < F; ni++){
      int col = n0 + wn * (TILE / 2) + ni * 16 + lc;
      float bvv = bias[col];
      #pragma unroll
      for(int rr = 0; rr < 4; rr++){
        int row = m0 + wm * (TILE / 2) + mi * 16 + g * 4 + rr;
        float v = acc[mi][ni][rr] + bvv;
        size_t idx = (size_t)row * N + col;
        if(MODE == 1) v = gelu_exact(v);
        if(MODE == 2) ((float*)outp)[idx] = v + resid[idx];
        else          ((unsigned short*)outp)[idx] = f2bf(v);
      }
    }
}

// ---------------- V transpose: qkv v-part (B,T,H,dh) -> vt (B,H,dh,T) ----------------
__global__ __launch_bounds__(256) void transpose_v(const unsigned short* __restrict__ qkv,
                                                   unsigned short* __restrict__ vt){
  __shared__ unsigned short tile[64][65];
  int t0 = blockIdx.x * 64; int bh = blockIdx.y;
  int b = bh / HH, h = bh % HH;
  int t = threadIdx.x;
  #pragma unroll
  for(int p = 0; p < 2; p++){
    int idx = p * 256 + t; int r = idx >> 3; int c = (idx & 7) * 8;
    bf16x8 v = *(const bf16x8*)(qkv + (size_t)(b * TT + t0 + r) * (3 * CC) + 2 * CC + h * DH + c);
    #pragma unroll
    for(int e = 0; e < 8; e++) tile[r][c + e] = (unsigned short)v[e];
  }
  __syncthreads();
  #pragma unroll
  for(int p = 0; p < 2; p++){
    int idx = p * 256 + t; int d = idx >> 3; int c = (idx & 7) * 8;
    bf16x8 v;
    #pragma unroll
    for(int e = 0; e < 8; e++) v[e] = (short)tile[c + e][d];
    *(bf16x8*)(vt + (size_t)(bh * DH + d) * TT + t0 + c) = v;
  }
}

// ---------------- Flash attention v5: lean softmax (no per-tile max), counted vmcnt ----
// Reference semantics: score[i,j] = k_i . q_j, mask j<=i, softmax over j.
// Swapped MFMA: S^T[j][i] at lane (g,lc): i=lc, j=js*16+g*4+rr.
// Softmax uses FIXED m_=0; overflow detected via rsum and handled by a rare
// exact path (full max reduce + rescale + recompute) -> correct for any input.
// Block mapping: xcd=o&7, qq=o>>3 -> head=xcd*3+qq%3, bx=31-qq/3.
__global__ __launch_bounds__(256) void attn_kernel(const unsigned short* __restrict__ qkv,
                                                   const unsigned short* __restrict__ vt,
                                                   const float* __restrict__ xln,
                                                   float* __restrict__ x1){
  __shared__ unsigned short Aq[2][64 * 64];
  __shared__ unsigned short Vs[2][64 * 64];
  __shared__ unsigned short Ps[4][16 * 64];
  int o = blockIdx.x;
  int xcd = o & 7, qq = o >> 3;          // qq 0..95
  int head = xcd * 3 + (qq % 3);         // 0..23
  int bx = 31 - qq / 3;                  // 31..0 (heavy first)
  int b = head / HH, h = head % HH;
  int t = threadIdx.x; int w = t >> 6; int l = t & 63;
  int g = l >> 4, lc = l & 15;
  int i0w = bx * 64 + w * 16;
  int irow = i0w + lc;
  unsigned short* pw = &Ps[w][0];
  const float SC = 0.125f * 1.44269504f;   // score scale into log2 domain

  // staging geometry: wave w, round p -> segment sgi=w*2+p (8 rows); lane l
  // covers row sgi*8 + (l>>3), linear cols (l&7)*8..+7; source col inverse-swizzled.
  int rl = l >> 3;
  int csrc = ((l & 7) * 8) ^ (rl * 8);

  bf16x8 bk[2];
  #pragma unroll
  for(int kk = 0; kk < 2; kk++)
    bk[kk] = *(const bf16x8*)(qkv + (size_t)(b * TT + irow) * (3 * CC) + CC + h * DH + kk * 32 + g * 8);

  float m_ = 0.0f, lsum = 0.f;   // fixed ref point; only moves via rare path
  f32x4 zero4 = {0.f, 0.f, 0.f, 0.f};
  f32x4 o4[4];
  #pragma unroll
  for(int ds = 0; ds < 4; ds++) o4[ds] = zero4;

  int NJT_w = (i0w + 16 + 63) >> 6;      // this wave's causal j-tile count
  int NJTmax = bx + 1;                   // block-wide j-tile count

  auto stage = [&](int j0, int cb){
    #pragma unroll
    for(int p = 0; p < 2; p++){
      int sgi = w * 2 + p;
      int row = sgi * 8 + rl;
      gload_lds16(qkv + (size_t)(b * TT + j0 + row) * (3 * CC) + h * DH + csrc, &Aq[cb][sgi * 512]);
      gload_lds16(vt  + (size_t)(head * DH + row) * TT + j0 + csrc,             &Vs[cb][sgi * 512]);
    }
  };

  stage(0, 0);
  if(NJTmax > 1) stage(64, 1);

  for(int jt = 0; jt < NJTmax; jt++){
    int j0 = jt * 64;
    int buf = jt & 1;
    if(jt + 1 < NJTmax) waitcnt_vm<4>(); else waitcnt_vm<0>();
    __builtin_amdgcn_s_barrier();
    if(jt < NJT_w){
      // QK^T (swapped): S^T[j][i]; A = q rows j (LDS), B = k rows i (reg)
      f32x4 s[4];
      __builtin_amdgcn_s_setprio(1);
      #pragma unroll
      for(int js = 0; js < 4; js++){
        s[js] = zero4;
        #pragma unroll
        for(int kk = 0; kk < 2; kk++){
          bf16x8 aq = *(const bf16x8*)&Aq[buf][swz(js * 16 + lc, kk * 32 + g * 8)];
          s[js] = __builtin_amdgcn_mfma_f32_16x16x32_bf16(aq, bk[kk], s[js], 0, 0, 0);
        }
      }
      __builtin_amdgcn_s_setprio(0);
      // causal mask only on diagonal tiles
      if(j0 + 63 > i0w){
        #pragma unroll
        for(int js = 0; js < 4; js++)
          #pragma unroll
          for(int rr = 0; rr < 4; rr++){
            int j = j0 + js * 16 + g * 4 + rr;
            if(j > irow) s[js][rr] = -1e30f;
          }
      }
      // common path: p = exp2(s*SC - m_*SC) with fixed m_; no max reduction
      float nmSC = -m_ * SC;
      f32x4 p[4];
      float rsum = 0.f;
      #pragma unroll
      for(int js = 0; js < 4; js++)
        #pragma unroll
        for(int rr = 0; rr < 4; rr++){
          float pv = exp2f(fmaf(s[js][rr], SC, nmSC));
          p[js][rr] = pv;
          rsum += pv;
        }
      rsum += __shfl_xor(rsum, 16, 64);
      rsum += __shfl_xor(rsum, 32, 64);
      if(__builtin_expect(__any(!(rsum < 1e30f)), 0)){
        // rare exact path: real max, rescale state, recompute p
        float mx = -1e30f;
        #pragma unroll
        for(int js = 0; js < 4; js++)
          #pragma unroll
          for(int rr = 0; rr < 4; rr++) mx = fmaxf(mx, s[js][rr]);
        mx = fmaxf(mx, __shfl_xor(mx, 16, 64));
        mx = fmaxf(mx, __shfl_xor(mx, 32, 64));
        float mn = fmaxf(m_, mx);
        float al = exp2f((m_ - mn) * SC);
        m_ = mn;
        lsum *= al;
        #pragma unroll
        for(int rr = 0; rr < 4; rr++){
          float alb = __shfl(al, g * 4 + rr, 64);
          #pragma unroll
          for(int ds = 0; ds < 4; ds++) o4[ds][rr] *= alb;
        }
        nmSC = -m_ * SC;
        rsum = 0.f;
        #pragma unroll
        for(int js = 0; js < 4; js++)
          #pragma unroll
          for(int rr = 0; rr < 4; rr++){
            float pv = exp2f(fmaf(s[js][rr], SC, nmSC));
            p[js][rr] = pv;
            rsum += pv;
          }
        rsum += __shfl_xor(rsum, 16, 64);
        rsum += __shfl_xor(rsum, 32, 64);
      }
      lsum += rsum;
      // P -> wave-private LDS (pw[i=lc][j], swizzled)
      #pragma unroll
      for(int js = 0; js < 4; js++){
        u16x4 pk;
        #pragma unroll
        for(int rr = 0; rr < 4; rr++) pk[rr] = f2bf(p[js][rr]);
        *(u16x4*)&pw[swz(lc, js * 16 + g * 4)] = pk;
      }
      bf16x8 pa[2];
      #pragma unroll
      for(int kk = 0; kk < 2; kk++)
        pa[kk] = *(const bf16x8*)&pw[swz(lc, kk * 32 + g * 8)];
      __builtin_amdgcn_s_setprio(1);
      #pragma unroll
      for(int ds = 0; ds < 4; ds++)
        #pragma unroll
        for(int kk = 0; kk < 2; kk++){
          bf16x8 vb = *(const bf16x8*)&Vs[buf][swz(ds * 16 + lc, kk * 32 + g * 8)];
          o4[ds] = __builtin_amdgcn_mfma_f32_16x16x32_bf16(pa[kk], vb, o4[ds], 0, 0, 0);
        }
      __builtin_amdgcn_s_setprio(0);
    }
    __builtin_amdgcn_s_barrier();
    if(jt + 2 < NJTmax) stage((jt + 2) * 64, buf);
  }
  // epilogue: o rows i = g*4+rr, cols d = ds*16+lc; softmax state lives at lane lc=i
  #pragma unroll
  for(int rr = 0; rr < 4; rr++){
    float lsb = __shfl(lsum, g * 4 + rr, 64);
    float rinv = 1.0f / lsb;
    int ig = i0w + g * 4 + rr;
    #pragma unroll
    for(int ds = 0; ds < 4; ds++){
      int col = h * DH + ds * 16 + lc;
      size_t idx = (size_t)(b * TT + ig) * CC + col;
      x1[idx] = xln[idx] + o4[ds][rr] * rinv;
    }
  }
}

// ---------------- host launcher ----------------
extern "C" void kernel_launch(void* const* d_in, const int* in_sizes, int n_in,
                              void* d_out, int out_size, void* d_ws, size_t ws_size,
                              hipStream_t stream){
  const float* x    = (const float*)d_in[0];
  const float* ln1g = (const float*)d_in[1];
  const float* ln1b = (const float*)d_in[2];
  const float* Wq   = (const float*)d_in[3];
  const float* bq   = (const float*)d_in[4];
  const float* Wk   = (const float*)d_in[5];
  const float* bk   = (const float*)d_in[6];
  const float* Wv   = (const float*)d_in[7];
  const float* bv   = (const float*)d_in[8];
  const float* ln2g = (const float*)d_in[9];
  const float* ln2b = (const float*)d_in[10];
  const float* W1   = (const float*)d_in[11];
  const float* b1   = (const float*)d_in[12];
  const float* W2   = (const float*)d_in[13];
  const float* b2   = (const float*)d_in[14];

  char* ws = (char*)d_ws;
  float*          xlnf = (float*)(ws + 0);                  // 12582912 B
  unsigned short* xlnb = (unsigned short*)(ws + 12582912);  // 6291456
  float*          x1   = (float*)(ws + 18874368);           // 12582912
  unsigned short* hln2 = (unsigned short*)(ws + 31457280);  // 6291456
  unsigned short* wqkv = (unsigned short*)(ws + 37748736);  // 3538944
  float*          bqkv = (float*)(ws + 41287680);           // 9216
  unsigned short* w1t  = (unsigned short*)(ws + 41296896);  // 4718592
  unsigned short* w2t  = (unsigned short*)(ws + 46015488);  // 4718592
  unsigned short* qkv  = (unsigned short*)(ws + 50734080);  // 18874368
  unsigned short* vt   = (unsigned short*)(ws + 69608448);  // 6291456
  unsigned short* mlp1 = (unsigned short*)(ws + 50734080);  // aliases qkv+vt (dead by then)

  transpose_convert_qkv<<<dim3(24, 24, 3), 256, 0, stream>>>(Wq, Wk, Wv, wqkv);
  transpose_convert<<<dim3(96, 24), 256, 0, stream>>>(W1, w1t, CC, 4 * CC);
  transpose_convert<<<dim3(24, 96), 256, 0, stream>>>(W2, w2t, 4 * CC, CC);
  concat_bias<<<9, 256, 0, stream>>>(bq, bk, bv, bqkv);

  ln_kernel<<<NROWS, 256, 0, stream>>>(x, ln1g, ln1b, xlnf, xlnb);

  gemm_bt<0, 128><<<dim3(18, 32), 256, 0, stream>>>(xlnb, wqkv, bqkv, nullptr, qkv, NROWS, 3 * CC, CC);

  transpose_v<<<dim3(TT / 64, BB * HH), 256, 0, stream>>>(qkv, vt);

  attn_kernel<<<dim3(768), 256, 0, stream>>>(qkv, vt, xlnf, x1);

  ln_kernel<<<NROWS, 256, 0, stream>>>(x1, ln2g, ln2b, nullptr, hln2);

  gemm_bt<1, 128><<<dim3(24, 32), 256, 0, stream>>>(hln2, w1t, b1, nullptr, mlp1, NROWS, 4 * CC, CC);

  gemm_bt<2, 64><<<dim3(12, 64), 256, 0, stream>>>(mlp1, w2t, b2, x1, d_out, NROWS, CC, 4 * CC);

  (void)in_sizes; (void)n_in; (void)out_size; (void)ws_size;
}